// Round 1
// 264.980 us; speedup vs baseline: 1.1011x; 1.1011x over previous
//
#include <hip/hip_runtime.h>
#include <math.h>

// Problem constants (fixed by setup_inputs)
constexpr int B_   = 2;
constexpr int C_   = 64;
constexpr int H_   = 128;
constexpr int W_   = 128;
constexpr int HW_  = H_ * W_;
constexpr int DG_  = 16;   // deformable groups
constexpr int KK_  = 9;    // 3x3 taps
constexpr int CG_  = 4;    // channels per group = C/DG
constexpr int OFFC_ = 3 * KK_ * DG_;  // 432
constexpr int R_   = C_ * KK_;        // 576 reduction length
constexpr int WP_  = 130;             // padded width/height
constexpr int HWP_ = WP_ * WP_;       // 16900 padded pixels

typedef _Float16 half8 __attribute__((ext_vector_type(8)));  // 8 f16 = 4 VGPR
typedef _Float16 half4 __attribute__((ext_vector_type(4)));  // 8-byte load/store
typedef float floatx4 __attribute__((ext_vector_type(4)));   // MFMA acc

// ---------------------------------------------------------------------------
// Generic MFMA A-operand prep: wA[(t*CH+h)*OC + oc][j] = f16(w[oc][(h*32+j)*9+t])
// ---------------------------------------------------------------------------
template <int OC, int CIN>
__global__ __launch_bounds__(256) void prep_wA_k(
    const float* __restrict__ w, _Float16* __restrict__ wA)
{
    constexpr int CH = CIN / 32;
    const int j = blockIdx.x * 256 + threadIdx.x;   // slab*OC*32 + oc*32 + jj
    if (j >= 9 * CH * OC * 32) return;
    const int slab = j / (OC * 32);
    const int rem  = j - slab * (OC * 32);
    const int oc   = rem >> 5;
    const int jj   = rem & 31;
    const int t    = slab / CH;
    const int h    = slab - t * CH;
    const int ic   = h * 32 + jj;
    wA[j] = (_Float16)w[(size_t)oc * (CIN * 9) + ic * 9 + t];
}

// ---------------------------------------------------------------------------
// Einsum A-operand prep: r = k*64 + gc (gc = g*4+c).  18 slabs of 32.
// ---------------------------------------------------------------------------
__global__ __launch_bounds__(256) void prep_wkA_k(
    const float* __restrict__ wk, _Float16* __restrict__ wkA)
{
    const int j = blockIdx.x * 256 + threadIdx.x;   // s*2048 + oc*32 + jj
    if (j >= 18 * 64 * 32) return;
    const int s   = j >> 11;
    const int rem = j & 2047;
    const int oc  = rem >> 5;
    const int jj  = rem & 31;
    const int k   = s >> 1;
    const int gc  = (s & 1) * 32 + jj;
    wkA[j] = (_Float16)wk[(size_t)oc * R_ + gc * 9 + k];
}

// ---------------------------------------------------------------------------
// NCHW fp32 -> PADDED slab-split f16: out[(c/32)*B + b][y+1][x+1][32].
// Borders pre-zeroed by hipMemsetAsync -> conv loads need no predication.
// ---------------------------------------------------------------------------
template <int CC>
__global__ __launch_bounds__(256) void nchw2slabpad_f16_k(
    const float* __restrict__ in, _Float16* __restrict__ outh)
{
    const int pix = blockIdx.x * 256 + threadIdx.x;
    const int b   = blockIdx.y;
    const int yp  = pix >> 7;
    const int xp  = pix & (W_ - 1);
    const float* ib = in + (size_t)b * CC * HW_ + pix;
#pragma unroll
    for (int c0 = 0; c0 < CC; c0 += 8) {
        half8 v;
#pragma unroll
        for (int j = 0; j < 8; ++j)
            v[j] = (_Float16)ib[(size_t)(c0 + j) * HW_];
        const int slab = c0 >> 5;
        *(half8*)&outh[((size_t)(slab * B_ + b) * HWP_
                        + (size_t)(yp + 1) * WP_ + (xp + 1)) * 32 + (c0 & 31)] = v;
    }
}

// ---------------------------------------------------------------------------
// NCHW fp32 -> plain NHWC f16 (for gather's x: half4 at g*4 within 64-rec).
// ---------------------------------------------------------------------------
template <int CC>
__global__ __launch_bounds__(256) void nchw2nhwc_f16_k(
    const float* __restrict__ in, _Float16* __restrict__ outh)
{
    const int pix = blockIdx.x * 256 + threadIdx.x;
    const int b   = blockIdx.y;
    const float* ib = in + (size_t)b * CC * HW_ + pix;
    _Float16* ob = outh + ((size_t)b * HW_ + pix) * CC;
#pragma unroll
    for (int c0 = 0; c0 < CC; c0 += 8) {
        half8 v;
#pragma unroll
        for (int j = 0; j < 8; ++j)
            v[j] = (_Float16)ib[(size_t)(c0 + j) * HW_];
        *(half8*)&ob[c0] = v;
    }
}

// ---------------------------------------------------------------------------
// Conv1/conv2 (CIN -> 64) via f16 MFMA, padded input -> UNCONDITIONAL loads,
// fully unrolled tap loop. Output padded slab-split f16.
// v2: wave tile = 64 oc x 16 px (mf=4) instead of 16x16. One B-fragment
// feeds 4 MFMAs; A deduped across the block's 4 waves via L1. Cache-side
// load traffic drops 4x (conv1: ~600 MB -> ~150 MB).
// ---------------------------------------------------------------------------
template <int CIN>
__global__ __launch_bounds__(256) void conv12_mfma_k(
    const _Float16* __restrict__ inp, const _Float16* __restrict__ wA,
    const float* __restrict__ bias, _Float16* __restrict__ outp)
{
    constexpr int CH = CIN / 32;
    const int tid  = threadIdx.x;
    const int lane = tid & 63;
    const int wv   = tid >> 6;
    const int l15  = lane & 15;
    const int quad = lane >> 4;

    const int zx   = blockIdx.x;          // (b*H + y)*2 + half64
    const int row  = zx >> 1;
    const int b    = row >> 7;
    const int y    = row & 127;
    const int px0  = (zx & 1) * 64 + wv * 16;

    floatx4 acc[4];
#pragma unroll
    for (int mf = 0; mf < 4; ++mf)
        acc[mf] = (floatx4){0.f, 0.f, 0.f, 0.f};

#pragma unroll
    for (int t = 0; t < 9; ++t) {
        const int dy = t / 3, dx = t % 3;
#pragma unroll
        for (int h = 0; h < CH; ++h) {
            const half8 bfr = *(const half8*)&inp[
                ((size_t)(h * B_ + b) * HWP_ + (size_t)(y + dy) * WP_
                 + (px0 + l15 + dx)) * 32 + quad * 8];
            const _Float16* ap = wA + ((size_t)(t * CH + h) * 64 + l15) * 32 + quad * 8;
#pragma unroll
            for (int mf = 0; mf < 4; ++mf) {
                const half8 afr = *(const half8*)&ap[(size_t)(mf * 16) * 32];
                acc[mf] = __builtin_amdgcn_mfma_f32_16x16x32_f16(afr, bfr, acc[mf], 0, 0, 0);
            }
        }
    }

    // epilogue: leaky ReLU, padded slab-split f16 store (8 B/lane x 4 tiles)
#pragma unroll
    for (int mf = 0; mf < 4; ++mf) {
        const int oc4 = mf * 16 + quad * 4;        // first of 4 output chans
        const float4 b4 = *(const float4*)&bias[oc4];
        half4 v4;
#pragma unroll
        for (int reg = 0; reg < 4; ++reg) {
            float r = acc[mf][reg] + ((const float*)&b4)[reg];
            r = (r >= 0.f) ? r : 0.1f * r;
            v4[reg] = (_Float16)r;
        }
        *(half4*)&outp[((size_t)((oc4 >> 5) * B_ + b) * HWP_
                        + (size_t)(y + 1) * WP_ + (px0 + l15 + 1)) * 32 + (oc4 & 31)] = v4;
    }
}

// ---------------------------------------------------------------------------
// Conv3 via f16 MFMA implicit GEMM, padded input, unconditional B loads,
// fully unrolled K loop, LDS-staged f16 omap epilogue.
// v2: wave tile = 144 oc x 32 px (mf=9), grid.y = 3 (was 48 oc, grid.y=9).
// Per K-step: 11 fragment loads feed 18 MFMAs (~29 FLOP/B, was 20);
// B re-read 3x instead of 9x across oc-tiles -> cache traffic ~830->~250 MB.
// Transform branch is now block-uniform (oc<288 <=> blockIdx.y<2); flow
// loads hoisted (slot == reg&1 -> 2 loads per nf).
// ---------------------------------------------------------------------------
__global__ __launch_bounds__(256) void conv3_mfma_k(
    const _Float16* __restrict__ h2p, const _Float16* __restrict__ w3A,
    const float* __restrict__ bias, const float* __restrict__ flow,
    _Float16* __restrict__ omh)
{
    __shared__ __align__(16) _Float16 Lds[144 * 132];   // 38016 B

    const int tid  = threadIdx.x;
    const int lane = tid & 63;
    const int wv   = tid >> 6;       // wave id 0..3
    const int l15  = lane & 15;
    const int quad = lane >> 4;

    const int row = blockIdx.x;      // b*128 + y
    const int b   = row >> 7;
    const int y   = row & 127;
    const int m0  = blockIdx.y * 144; // oc tile base (0,144,288)
    const int px0 = wv * 32;

    floatx4 acc[9][2];
#pragma unroll
    for (int mf = 0; mf < 9; ++mf)
#pragma unroll
        for (int nf = 0; nf < 2; ++nf)
            acc[mf][nf] = (floatx4){0.f, 0.f, 0.f, 0.f};

#pragma unroll
    for (int t = 0; t < 9; ++t) {
        const int dy = t / 3, dx = t % 3;
#pragma unroll
        for (int h = 0; h < 2; ++h) {        // two 32-ic slabs of K
            half8 bfr[2];
#pragma unroll
            for (int nf = 0; nf < 2; ++nf)
                bfr[nf] = *(const half8*)&h2p[
                    ((size_t)(h * B_ + b) * HWP_ + (size_t)(y + dy) * WP_
                     + (px0 + nf * 16 + l15 + dx)) * 32 + quad * 8];
            const _Float16* wbase = w3A + ((size_t)(t * 2 + h) * OFFC_ + m0 + l15) * 32 + quad * 8;
#pragma unroll
            for (int mf = 0; mf < 9; ++mf) {
                const half8 afr = *(const half8*)&wbase[(size_t)(mf * 16) * 32];
#pragma unroll
                for (int nf = 0; nf < 2; ++nf)
                    acc[mf][nf] = __builtin_amdgcn_mfma_f32_16x16x32_f16(
                        afr, bfr[nf], acc[mf][nf], 0, 0, 0);
            }
        }
    }

    // ---- transform + stage to LDS (f16, 144 rows x 128 px, pad to 132) ----
    const bool is_off = (blockIdx.y < 2);     // block-uniform channel class
    float flY[2], flX[2];
#pragma unroll
    for (int nf = 0; nf < 2; ++nf) {
        const int px = px0 + nf * 16 + l15;
        if (is_off) {
            flY[nf] = flow[(size_t)(b * 2 + 1) * HW_ + y * W_ + px]; // slot 0 (y)
            flX[nf] = flow[(size_t)(b * 2 + 0) * HW_ + y * W_ + px]; // slot 1 (x)
        }
    }
#pragma unroll
    for (int mf = 0; mf < 9; ++mf) {
        const float4 b4 = *(const float4*)&bias[m0 + mf * 16 + quad * 4];
#pragma unroll
        for (int nf = 0; nf < 2; ++nf) {
            const int px = px0 + nf * 16 + l15;
#pragma unroll
            for (int reg = 0; reg < 4; ++reg) {
                const int ocl = mf * 16 + quad * 4 + reg;   // 0..143
                float val = acc[mf][nf][reg] + ((const float*)&b4)[reg];
                if (is_off) {                       // offset channels
                    const int slot = reg & 1;       // 0 = y, 1 = x
                    const float fl = slot ? flX[nf] : flY[nf];
                    const float e = __expf(2.f * val);      // tanh via exp
                    val = 10.f * (1.f - __fdividef(2.f, e + 1.f)) + fl;
                } else {                            // mask channels: sigmoid
                    val = __fdividef(1.f, 1.f + __expf(-val));
                }
                Lds[ocl * 132 + px] = (_Float16)val;
            }
        }
    }
    __syncthreads();   // single barrier; LDS read-only hereafter

    // ---- contiguous f16 copy-out: 144 plane-rows x 128 px ----
#pragma unroll
    for (int it = 0; it < 18; ++it) {
        const int j4 = it * 256 + tid;
        const int r  = j4 >> 5;          // 0..143
        const int c4 = j4 & 31;          // half4 col
        const int oc = m0 + r;
        int g, k, slot;
        if (oc < 2 * DG_ * KK_) {
            g = oc / 18;
            const int rem = oc - g * 18;
            k = rem >> 1;
            slot = rem & 1;
        } else {
            const int c = oc - 2 * DG_ * KK_;
            g = c / 9;
            k = c - g * 9;
            slot = 2;
        }
        const half4 hv = *(const half4*)&Lds[r * 132 + c4 * 4];
        *(half4*)&omh[((size_t)((b * DG_ * KK_ + g * KK_ + k) * 3 + slot)) * HW_
                      + y * W_ + c4 * 4] = hv;
    }
}

// ---------------------------------------------------------------------------
// Phase A: bilinear gather -> SLAB-SPLIT f16 val: [(s*B+b)*HW+pix][32],
// s = k*2 + g/8. Lane map: tid&15 = g, tid>>4 = pixel-local (16 px/block).
// 16 lanes (one pixel's 16 g's) write 128 contiguous B -> full-granule
// HBM writes (was 16-B segments). Grid (HW/16, B*9) = 9216 blocks.
// ---------------------------------------------------------------------------
__global__ __launch_bounds__(256) void gather_k(
    const _Float16* __restrict__ xn, const _Float16* __restrict__ omh,
    _Float16* __restrict__ valh)
{
    const int tid = threadIdx.x;
    const int g   = tid & 15;
    const int pl  = tid >> 4;                 // 0..15 pixel local
    const int pix = blockIdx.x * 16 + pl;
    const int zy  = blockIdx.y;               // b*9 + k
    const int b   = zy / KK_;
    const int k   = zy - b * KK_;
    const int yp  = pix >> 7;
    const int xp  = pix & (W_ - 1);

    const size_t obase = ((size_t)((b * DG_ + g) * KK_ + k) * 3) * HW_ + pix;
    const float oy = (float)omh[obase];
    const float ox = (float)omh[obase + HW_];
    const float m  = (float)omh[obase + 2 * HW_];

    const float py = (float)(yp + (k / 3) - 1) + oy;
    const float px = (float)(xp + (k % 3) - 1) + ox;
    const float y0f = floorf(py);
    const float x0f = floorf(px);
    const float wy = py - y0f;
    const float wx = px - x0f;
    const int y0 = (int)y0f, x0 = (int)x0f;
    const int y1 = y0 + 1,  x1 = x0 + 1;
    const bool vy0 = ((unsigned)y0 < (unsigned)H_);
    const bool vy1 = ((unsigned)y1 < (unsigned)H_);
    const bool vx0 = ((unsigned)x0 < (unsigned)W_);
    const bool vx1 = ((unsigned)x1 < (unsigned)W_);
    const float w00 = vy0 && vx0 ? (1.f - wy) * (1.f - wx) : 0.f;
    const float w01 = vy0 && vx1 ? (1.f - wy) * wx         : 0.f;
    const float w10 = vy1 && vx0 ? wy * (1.f - wx)         : 0.f;
    const float w11 = vy1 && vx1 ? wy * wx                 : 0.f;
    const int i00 = (vy0 && vx0) ? y0 * W_ + x0 : 0;
    const int i01 = (vy0 && vx1) ? y0 * W_ + x1 : 0;
    const int i10 = (vy1 && vx0) ? y1 * W_ + x0 : 0;
    const int i11 = (vy1 && vx1) ? y1 * W_ + x1 : 0;

    const _Float16* xb = xn + (size_t)b * HW_ * C_ + g * CG_;
    const half4 p00 = *(const half4*)&xb[(size_t)i00 * C_];
    const half4 p01 = *(const half4*)&xb[(size_t)i01 * C_];
    const half4 p10 = *(const half4*)&xb[(size_t)i10 * C_];
    const half4 p11 = *(const half4*)&xb[(size_t)i11 * C_];

    half4 v4;
#pragma unroll
    for (int c = 0; c < CG_; ++c) {
        float v = w00 * (float)p00[c] + w01 * (float)p01[c]
                + w10 * (float)p10[c] + w11 * (float)p11[c];
        v4[c] = (_Float16)(v * m);
    }
    const int s = k * 2 + (g >> 3);
    *(half4*)&valh[((size_t)(s * B_ + b) * HW_ + pix) * 32 + (g & 7) * 4] = v4;
}

// ---------------------------------------------------------------------------
// Phase B: einsum via f16 MFMA, SINGLE PASS (no K-split, no partials).
// Slab-split valh -> B-fragment load = 16 consecutive 64-B records = 1 KB
// contiguous. Wave = 16 px (nf=1) x 64 oc (mf=4); block = 4 waves = 64 px;
// grid = B*HW/64 = 512 blocks. Output staged in LDS (write-once -> barrier
// -> read-only) and copied to d_out in 256-B coalesced segments.
// ---------------------------------------------------------------------------
__global__ __launch_bounds__(256) void einsum_mfma_k(
    const _Float16* __restrict__ valh, const _Float16* __restrict__ wkA,
    float* __restrict__ out)
{
    __shared__ __align__(16) float Lds[64 * 68];   // 64 oc x 64 px (pad 68)

    const int tid  = threadIdx.x;
    const int lane = tid & 63;
    const int wv   = tid >> 6;
    const int l15  = lane & 15;
    const int quad = lane >> 4;

    const int pixg0 = blockIdx.x * 64 + wv * 16;    // global pixel (b*HW+pix)
    const int b     = pixg0 >> 14;
    const int pix0  = pixg0 & (HW_ - 1);

    floatx4 acc[4];
#pragma unroll
    for (int mf = 0; mf < 4; ++mf)
        acc[mf] = (floatx4){0.f, 0.f, 0.f, 0.f};

#pragma unroll
    for (int s = 0; s < 18; ++s) {
        const half8 bfr = *(const half8*)&valh[
            ((size_t)(s * B_ + b) * HW_ + pix0 + l15) * 32 + quad * 8];
        const _Float16* ap = wkA + (size_t)s * 64 * 32;
#pragma unroll
        for (int mf = 0; mf < 4; ++mf) {
            const half8 afr = *(const half8*)&ap[(mf * 16 + l15) * 32 + quad * 8];
            acc[mf] = __builtin_amdgcn_mfma_f32_16x16x32_f16(afr, bfr, acc[mf], 0, 0, 0);
        }
    }

    // ---- stage 64 oc x 64 px tile to LDS ----
    const int pxl = wv * 16 + l15;                  // 0..63 block-local pixel
#pragma unroll
    for (int mf = 0; mf < 4; ++mf)
#pragma unroll
        for (int reg = 0; reg < 4; ++reg)
            Lds[(mf * 16 + quad * 4 + reg) * 68 + pxl] = acc[mf][reg];
    __syncthreads();   // single barrier; LDS read-only hereafter

    // ---- coalesced copy-out: 64 oc-rows x 64 px (16 float4 per row) ----
    const int pixb = blockIdx.x * 64 & (HW_ - 1);   // block-base pixel
#pragma unroll
    for (int it = 0; it < 4; ++it) {
        const int j4 = it * 256 + tid;
        const int r  = j4 >> 4;                     // oc 0..63
        const int c4 = j4 & 15;                     // float4 col
        float4 v;
        v.x = Lds[r * 68 + c4 * 4 + 0];
        v.y = Lds[r * 68 + c4 * 4 + 1];
        v.z = Lds[r * 68 + c4 * 4 + 2];
        v.w = Lds[r * 68 + c4 * 4 + 3];
        *(float4*)&out[((size_t)(b * C_ + r)) * HW_ + pixb + c4 * 4] = v;
    }
}

// ---------------------------------------------------------------------------
extern "C" void kernel_launch(void* const* d_in, const int* in_sizes, int n_in,
                              void* d_out, int out_size, void* d_ws, size_t ws_size,
                              hipStream_t stream)
{
    const float* x    = (const float*)d_in[0];
    const float* ef   = (const float*)d_in[1];
    const float* flow = (const float*)d_in[2];
    const float* w1   = (const float*)d_in[3];
    const float* b1   = (const float*)d_in[4];
    const float* w2   = (const float*)d_in[5];
    const float* b2   = (const float*)d_in[6];
    const float* w3   = (const float*)d_in[7];
    const float* b3   = (const float*)d_in[8];
    const float* wk   = (const float*)d_in[9];
    float* out = (float*)d_out;

    // Workspace (half slots):
    //   omh 14,155,776 | valh 18,874,368 | ef_p 4*B*HWP*32 = 4,326,400
    //   xn 2,097,152 | h1p 2*B*HWP*32 = 2,163,200 | h2p 2,163,200
    //   w1A 73,728 | w2A 36,864 | w3A 248,832 | wkA 36,864
    _Float16* omh  = (_Float16*)d_ws;
    _Float16* valh = omh + (size_t)B_ * OFFC_ * HW_;
    _Float16* ef_p = valh + (size_t)18 * B_ * HW_ * 32;
    _Float16* xn   = ef_p + (size_t)4 * B_ * HWP_ * 32;
    _Float16* h1p  = xn + (size_t)B_ * HW_ * 64;
    _Float16* h2p  = h1p + (size_t)2 * B_ * HWP_ * 32;
    _Float16* w1A  = h2p + (size_t)2 * B_ * HWP_ * 32;
    _Float16* w2A  = w1A + 64 * 128 * 9;
    _Float16* w3A  = w2A + 64 * 64 * 9;
    _Float16* wkA  = w3A + OFFC_ * 64 * 9;

    // Zero the padded buffers (borders must be 0; interiors overwritten).
    hipMemsetAsync(ef_p, 0, (size_t)4 * B_ * HWP_ * 32 * 2, stream);
    hipMemsetAsync(h1p, 0, (size_t)2 * B_ * HWP_ * 32 * 2, stream);
    hipMemsetAsync(h2p, 0, (size_t)2 * B_ * HWP_ * 32 * 2, stream);

    prep_wA_k<64, 128><<<dim3((64 * 128 * 9 + 255) / 256), 256, 0, stream>>>(w1, w1A);
    prep_wA_k<64, 64><<<dim3((64 * 64 * 9 + 255) / 256), 256, 0, stream>>>(w2, w2A);
    prep_wA_k<OFFC_, 64><<<dim3((OFFC_ * 64 * 9 + 255) / 256), 256, 0, stream>>>(w3, w3A);
    prep_wkA_k<<<dim3((18 * 64 * 32 + 255) / 256), 256, 0, stream>>>(wk, wkA);
    nchw2slabpad_f16_k<128><<<dim3(HW_ / 256, B_), 256, 0, stream>>>(ef, ef_p);
    nchw2nhwc_f16_k<64><<<dim3(HW_ / 256, B_), 256, 0, stream>>>(x, xn);

    conv12_mfma_k<128><<<dim3(B_ * H_ * 2), 256, 0, stream>>>(ef_p, w1A, b1, h1p);
    conv12_mfma_k<64><<<dim3(B_ * H_ * 2), 256, 0, stream>>>(h1p, w2A, b2, h2p);
    conv3_mfma_k<<<dim3(B_ * H_, 3), 256, 0, stream>>>(h2p, w3A, b3, flow, omh);

    gather_k<<<dim3(HW_ / 16, B_ * KK_), 256, 0, stream>>>(xn, omh, valh);
    einsum_mfma_k<<<dim3(B_ * HW_ / 64), 256, 0, stream>>>(valh, wkA, out);
}

// Round 2
// 240.154 us; speedup vs baseline: 1.2149x; 1.1034x over previous
//
#include <hip/hip_runtime.h>
#include <math.h>

// Problem constants (fixed by setup_inputs)
constexpr int B_   = 2;
constexpr int C_   = 64;
constexpr int H_   = 128;
constexpr int W_   = 128;
constexpr int HW_  = H_ * W_;
constexpr int DG_  = 16;   // deformable groups
constexpr int KK_  = 9;    // 3x3 taps
constexpr int CG_  = 4;    // channels per group = C/DG
constexpr int OFFC_ = 3 * KK_ * DG_;  // 432
constexpr int R_   = C_ * KK_;        // 576 reduction length
constexpr int WP_  = 130;             // padded width/height
constexpr int HWP_ = WP_ * WP_;       // 16900 padded pixels

typedef _Float16 half8 __attribute__((ext_vector_type(8)));  // 8 f16 = 4 VGPR
typedef _Float16 half4 __attribute__((ext_vector_type(4)));  // 8-byte load/store
typedef float floatx4 __attribute__((ext_vector_type(4)));   // MFMA acc

// ---------------------------------------------------------------------------
// Generic MFMA A-operand prep: wA[(t*CH+h)*OC + oc][j] = f16(w[oc][(h*32+j)*9+t])
// ---------------------------------------------------------------------------
template <int OC, int CIN>
__global__ __launch_bounds__(256) void prep_wA_k(
    const float* __restrict__ w, _Float16* __restrict__ wA)
{
    constexpr int CH = CIN / 32;
    const int j = blockIdx.x * 256 + threadIdx.x;   // slab*OC*32 + oc*32 + jj
    if (j >= 9 * CH * OC * 32) return;
    const int slab = j / (OC * 32);
    const int rem  = j - slab * (OC * 32);
    const int oc   = rem >> 5;
    const int jj   = rem & 31;
    const int t    = slab / CH;
    const int h    = slab - t * CH;
    const int ic   = h * 32 + jj;
    wA[j] = (_Float16)w[(size_t)oc * (CIN * 9) + ic * 9 + t];
}

// ---------------------------------------------------------------------------
// Einsum A-operand prep: r = k*64 + gc (gc = g*4+c).  18 slabs of 32.
// ---------------------------------------------------------------------------
__global__ __launch_bounds__(256) void prep_wkA_k(
    const float* __restrict__ wk, _Float16* __restrict__ wkA)
{
    const int j = blockIdx.x * 256 + threadIdx.x;   // s*2048 + oc*32 + jj
    if (j >= 18 * 64 * 32) return;
    const int s   = j >> 11;
    const int rem = j & 2047;
    const int oc  = rem >> 5;
    const int jj  = rem & 31;
    const int k   = s >> 1;
    const int gc  = (s & 1) * 32 + jj;
    wkA[j] = (_Float16)wk[(size_t)oc * R_ + gc * 9 + k];
}

// ---------------------------------------------------------------------------
// NCHW fp32 -> PADDED slab-split f16: out[(c/32)*B + b][y+1][x+1][32].
// Borders pre-zeroed by hipMemsetAsync -> conv loads need no predication.
// ---------------------------------------------------------------------------
template <int CC>
__global__ __launch_bounds__(256) void nchw2slabpad_f16_k(
    const float* __restrict__ in, _Float16* __restrict__ outh)
{
    const int pix = blockIdx.x * 256 + threadIdx.x;
    const int b   = blockIdx.y;
    const int yp  = pix >> 7;
    const int xp  = pix & (W_ - 1);
    const float* ib = in + (size_t)b * CC * HW_ + pix;
#pragma unroll
    for (int c0 = 0; c0 < CC; c0 += 8) {
        half8 v;
#pragma unroll
        for (int j = 0; j < 8; ++j)
            v[j] = (_Float16)ib[(size_t)(c0 + j) * HW_];
        const int slab = c0 >> 5;
        *(half8*)&outh[((size_t)(slab * B_ + b) * HWP_
                        + (size_t)(yp + 1) * WP_ + (xp + 1)) * 32 + (c0 & 31)] = v;
    }
}

// ---------------------------------------------------------------------------
// NCHW fp32 -> per-group planes f16: xg[((b*DG+g)*HW + pix)*4 + c].
// Gather's taps for fixed g then read 8-B records at consecutive pixels ->
// neighboring lanes share cache lines instead of touching 64 distinct ones.
// ---------------------------------------------------------------------------
__global__ __launch_bounds__(256) void nchw2gx_f16_k(
    const float* __restrict__ in, _Float16* __restrict__ outh)
{
    const int pix = blockIdx.x * 256 + threadIdx.x;
    const int b   = blockIdx.y;
    const float* ib = in + (size_t)b * C_ * HW_ + pix;
#pragma unroll
    for (int g = 0; g < DG_; ++g) {
        half4 v;
#pragma unroll
        for (int c = 0; c < 4; ++c)
            v[c] = (_Float16)ib[(size_t)(g * 4 + c) * HW_];
        *(half4*)&outh[((size_t)(b * DG_ + g) * HW_ + pix) * 4] = v;
    }
}

// ---------------------------------------------------------------------------
// Conv1/conv2 (CIN -> 64) via f16 MFMA, padded input -> UNCONDITIONAL loads,
// fully unrolled tap loop. Output padded slab-split f16.
// Wave tile = 64 oc x 16 px (mf=4); one B-fragment feeds 4 MFMAs.
// ---------------------------------------------------------------------------
template <int CIN>
__global__ __launch_bounds__(256) void conv12_mfma_k(
    const _Float16* __restrict__ inp, const _Float16* __restrict__ wA,
    const float* __restrict__ bias, _Float16* __restrict__ outp)
{
    constexpr int CH = CIN / 32;
    const int tid  = threadIdx.x;
    const int lane = tid & 63;
    const int wv   = tid >> 6;
    const int l15  = lane & 15;
    const int quad = lane >> 4;

    const int zx   = blockIdx.x;          // (b*H + y)*2 + half64
    const int row  = zx >> 1;
    const int b    = row >> 7;
    const int y    = row & 127;
    const int px0  = (zx & 1) * 64 + wv * 16;

    floatx4 acc[4];
#pragma unroll
    for (int mf = 0; mf < 4; ++mf)
        acc[mf] = (floatx4){0.f, 0.f, 0.f, 0.f};

#pragma unroll
    for (int t = 0; t < 9; ++t) {
        const int dy = t / 3, dx = t % 3;
#pragma unroll
        for (int h = 0; h < CH; ++h) {
            const half8 bfr = *(const half8*)&inp[
                ((size_t)(h * B_ + b) * HWP_ + (size_t)(y + dy) * WP_
                 + (px0 + l15 + dx)) * 32 + quad * 8];
            const _Float16* ap = wA + ((size_t)(t * CH + h) * 64 + l15) * 32 + quad * 8;
#pragma unroll
            for (int mf = 0; mf < 4; ++mf) {
                const half8 afr = *(const half8*)&ap[(size_t)(mf * 16) * 32];
                acc[mf] = __builtin_amdgcn_mfma_f32_16x16x32_f16(afr, bfr, acc[mf], 0, 0, 0);
            }
        }
    }

    // epilogue: leaky ReLU, padded slab-split f16 store (8 B/lane x 4 tiles)
#pragma unroll
    for (int mf = 0; mf < 4; ++mf) {
        const int oc4 = mf * 16 + quad * 4;        // first of 4 output chans
        const float4 b4 = *(const float4*)&bias[oc4];
        half4 v4;
#pragma unroll
        for (int reg = 0; reg < 4; ++reg) {
            float r = acc[mf][reg] + ((const float*)&b4)[reg];
            r = (r >= 0.f) ? r : 0.1f * r;
            v4[reg] = (_Float16)r;
        }
        *(half4*)&outp[((size_t)((oc4 >> 5) * B_ + b) * HWP_
                        + (size_t)(y + 1) * WP_ + (px0 + l15 + 1)) * 32 + (oc4 & 31)] = v4;
    }
}

// ---------------------------------------------------------------------------
// Conv3 via f16 MFMA implicit GEMM, padded input, unconditional B loads,
// fully unrolled K loop, LDS-staged f16 omap epilogue.
// Wave tile = 144 oc x 32 px (mf=9), grid.y = 3.
// ---------------------------------------------------------------------------
__global__ __launch_bounds__(256) void conv3_mfma_k(
    const _Float16* __restrict__ h2p, const _Float16* __restrict__ w3A,
    const float* __restrict__ bias, const float* __restrict__ flow,
    _Float16* __restrict__ omh)
{
    __shared__ __align__(16) _Float16 Lds[144 * 132];   // 38016 B

    const int tid  = threadIdx.x;
    const int lane = tid & 63;
    const int wv   = tid >> 6;       // wave id 0..3
    const int l15  = lane & 15;
    const int quad = lane >> 4;

    const int row = blockIdx.x;      // b*128 + y
    const int b   = row >> 7;
    const int y   = row & 127;
    const int m0  = blockIdx.y * 144; // oc tile base (0,144,288)
    const int px0 = wv * 32;

    floatx4 acc[9][2];
#pragma unroll
    for (int mf = 0; mf < 9; ++mf)
#pragma unroll
        for (int nf = 0; nf < 2; ++nf)
            acc[mf][nf] = (floatx4){0.f, 0.f, 0.f, 0.f};

#pragma unroll
    for (int t = 0; t < 9; ++t) {
        const int dy = t / 3, dx = t % 3;
#pragma unroll
        for (int h = 0; h < 2; ++h) {        // two 32-ic slabs of K
            half8 bfr[2];
#pragma unroll
            for (int nf = 0; nf < 2; ++nf)
                bfr[nf] = *(const half8*)&h2p[
                    ((size_t)(h * B_ + b) * HWP_ + (size_t)(y + dy) * WP_
                     + (px0 + nf * 16 + l15 + dx)) * 32 + quad * 8];
            const _Float16* wbase = w3A + ((size_t)(t * 2 + h) * OFFC_ + m0 + l15) * 32 + quad * 8;
#pragma unroll
            for (int mf = 0; mf < 9; ++mf) {
                const half8 afr = *(const half8*)&wbase[(size_t)(mf * 16) * 32];
#pragma unroll
                for (int nf = 0; nf < 2; ++nf)
                    acc[mf][nf] = __builtin_amdgcn_mfma_f32_16x16x32_f16(
                        afr, bfr[nf], acc[mf][nf], 0, 0, 0);
            }
        }
    }

    // ---- transform + stage to LDS (f16, 144 rows x 128 px, pad to 132) ----
    const bool is_off = (blockIdx.y < 2);     // block-uniform channel class
    float flY[2], flX[2];
#pragma unroll
    for (int nf = 0; nf < 2; ++nf) {
        const int px = px0 + nf * 16 + l15;
        if (is_off) {
            flY[nf] = flow[(size_t)(b * 2 + 1) * HW_ + y * W_ + px]; // slot 0 (y)
            flX[nf] = flow[(size_t)(b * 2 + 0) * HW_ + y * W_ + px]; // slot 1 (x)
        }
    }
#pragma unroll
    for (int mf = 0; mf < 9; ++mf) {
        const float4 b4 = *(const float4*)&bias[m0 + mf * 16 + quad * 4];
#pragma unroll
        for (int nf = 0; nf < 2; ++nf) {
            const int px = px0 + nf * 16 + l15;
#pragma unroll
            for (int reg = 0; reg < 4; ++reg) {
                const int ocl = mf * 16 + quad * 4 + reg;   // 0..143
                float val = acc[mf][nf][reg] + ((const float*)&b4)[reg];
                if (is_off) {                       // offset channels
                    const int slot = reg & 1;       // 0 = y, 1 = x
                    const float fl = slot ? flX[nf] : flY[nf];
                    const float e = __expf(2.f * val);      // tanh via exp
                    val = 10.f * (1.f - __fdividef(2.f, e + 1.f)) + fl;
                } else {                            // mask channels: sigmoid
                    val = __fdividef(1.f, 1.f + __expf(-val));
                }
                Lds[ocl * 132 + px] = (_Float16)val;
            }
        }
    }
    __syncthreads();   // single barrier; LDS read-only hereafter

    // ---- contiguous f16 copy-out: 144 plane-rows x 128 px ----
#pragma unroll
    for (int it = 0; it < 18; ++it) {
        const int j4 = it * 256 + tid;
        const int r  = j4 >> 5;          // 0..143
        const int c4 = j4 & 31;          // half4 col
        const int oc = m0 + r;
        int g, k, slot;
        if (oc < 2 * DG_ * KK_) {
            g = oc / 18;
            const int rem = oc - g * 18;
            k = rem >> 1;
            slot = rem & 1;
        } else {
            const int c = oc - 2 * DG_ * KK_;
            g = c / 9;
            k = c - g * 9;
            slot = 2;
        }
        const half4 hv = *(const half4*)&Lds[r * 132 + c4 * 4];
        *(half4*)&omh[((size_t)((b * DG_ * KK_ + g * KK_ + k) * 3 + slot)) * HW_
                      + y * W_ + c4 * 4] = hv;
    }
}

// ---------------------------------------------------------------------------
// Phase A: bilinear gather, PIXEL-MAJOR lanes. Thread = one pixel for a
// fixed (b,k); loops g=0..15 in registers. omh reads are fully coalesced;
// tap loads for fixed g hit consecutive 8-B records of the g-plane ->
// neighboring lanes share cache lines (~6-12 lines/wave vs 64 before).
// Thread assembles both 64-B valh records (slabs 2k, 2k+1) and writes them
// as 8 contiguous 16-B stores. Grid (HW/256, B*9) = 1152 blocks.
// ---------------------------------------------------------------------------
__global__ __launch_bounds__(256) void gather_k(
    const _Float16* __restrict__ xg, const _Float16* __restrict__ omh,
    _Float16* __restrict__ valh)
{
    const int tid = threadIdx.x;
    const int pix = blockIdx.x * 256 + tid;
    const int zy  = blockIdx.y;               // b*9 + k
    const int b   = zy / KK_;
    const int k   = zy - b * KK_;
    const int yp  = pix >> 7;
    const int xp  = pix & (W_ - 1);
    const float fy = (float)(yp + (k / 3) - 1);
    const float fx = (float)(xp + (k % 3) - 1);

    half4 rec[16];
#pragma unroll
    for (int g = 0; g < DG_; ++g) {
        const size_t obase = ((size_t)((b * DG_ + g) * KK_ + k) * 3) * HW_ + pix;
        const float oy = (float)omh[obase];
        const float ox = (float)omh[obase + HW_];
        const float m  = (float)omh[obase + 2 * HW_];

        const float py = fy + oy;
        const float px = fx + ox;
        const float y0f = floorf(py);
        const float x0f = floorf(px);
        const float wy = py - y0f;
        const float wx = px - x0f;
        const int y0 = (int)y0f, x0 = (int)x0f;
        const int y1 = y0 + 1,  x1 = x0 + 1;
        const bool vy0 = ((unsigned)y0 < (unsigned)H_);
        const bool vy1 = ((unsigned)y1 < (unsigned)H_);
        const bool vx0 = ((unsigned)x0 < (unsigned)W_);
        const bool vx1 = ((unsigned)x1 < (unsigned)W_);
        const float w00 = vy0 && vx0 ? (1.f - wy) * (1.f - wx) : 0.f;
        const float w01 = vy0 && vx1 ? (1.f - wy) * wx         : 0.f;
        const float w10 = vy1 && vx0 ? wy * (1.f - wx)         : 0.f;
        const float w11 = vy1 && vx1 ? wy * wx                 : 0.f;
        const int i00 = (vy0 && vx0) ? y0 * W_ + x0 : 0;
        const int i01 = (vy0 && vx1) ? y0 * W_ + x1 : 0;
        const int i10 = (vy1 && vx0) ? y1 * W_ + x0 : 0;
        const int i11 = (vy1 && vx1) ? y1 * W_ + x1 : 0;

        const _Float16* xb = xg + (size_t)(b * DG_ + g) * HW_ * 4;
        const half4 p00 = *(const half4*)&xb[(size_t)i00 * 4];
        const half4 p01 = *(const half4*)&xb[(size_t)i01 * 4];
        const half4 p10 = *(const half4*)&xb[(size_t)i10 * 4];
        const half4 p11 = *(const half4*)&xb[(size_t)i11 * 4];

        half4 v4;
#pragma unroll
        for (int c = 0; c < CG_; ++c) {
            float v = w00 * (float)p00[c] + w01 * (float)p01[c]
                    + w10 * (float)p10[c] + w11 * (float)p11[c];
            v4[c] = (_Float16)(v * m);
        }
        rec[g] = v4;
    }

    // write slabs s = 2k (g 0..7) and 2k+1 (g 8..15): 64 B each, contiguous
    _Float16* r0 = &valh[((size_t)((2 * k) * B_ + b) * HW_ + pix) * 32];
    _Float16* r1 = &valh[((size_t)((2 * k + 1) * B_ + b) * HW_ + pix) * 32];
#pragma unroll
    for (int j = 0; j < 4; ++j) {
        half8 w0, w1;
#pragma unroll
        for (int c = 0; c < 4; ++c) {
            w0[c]     = rec[2 * j][c];
            w0[c + 4] = rec[2 * j + 1][c];
            w1[c]     = rec[8 + 2 * j][c];
            w1[c + 4] = rec[9 + 2 * j][c];
        }
        *(half8*)&r0[j * 8] = w0;
        *(half8*)&r1[j * 8] = w1;
    }
}

// ---------------------------------------------------------------------------
// Phase B: einsum via f16 MFMA, SINGLE PASS (no K-split, no partials).
// Slab-split valh -> B-fragment load = 16 consecutive 64-B records = 1 KB
// contiguous. Wave = 16 px (nf=1) x 64 oc (mf=4); block = 4 waves = 64 px;
// grid = B*HW/64 = 512 blocks. Output staged in LDS (write-once -> barrier
// -> read-only) and copied to d_out in 256-B coalesced segments.
// ---------------------------------------------------------------------------
__global__ __launch_bounds__(256) void einsum_mfma_k(
    const _Float16* __restrict__ valh, const _Float16* __restrict__ wkA,
    float* __restrict__ out)
{
    __shared__ __align__(16) float Lds[64 * 68];   // 64 oc x 64 px (pad 68)

    const int tid  = threadIdx.x;
    const int lane = tid & 63;
    const int wv   = tid >> 6;
    const int l15  = lane & 15;
    const int quad = lane >> 4;

    const int pixg0 = blockIdx.x * 64 + wv * 16;    // global pixel (b*HW+pix)
    const int b     = pixg0 >> 14;
    const int pix0  = pixg0 & (HW_ - 1);

    floatx4 acc[4];
#pragma unroll
    for (int mf = 0; mf < 4; ++mf)
        acc[mf] = (floatx4){0.f, 0.f, 0.f, 0.f};

#pragma unroll
    for (int s = 0; s < 18; ++s) {
        const half8 bfr = *(const half8*)&valh[
            ((size_t)(s * B_ + b) * HW_ + pix0 + l15) * 32 + quad * 8];
        const _Float16* ap = wkA + (size_t)s * 64 * 32;
#pragma unroll
        for (int mf = 0; mf < 4; ++mf) {
            const half8 afr = *(const half8*)&ap[(mf * 16 + l15) * 32 + quad * 8];
            acc[mf] = __builtin_amdgcn_mfma_f32_16x16x32_f16(afr, bfr, acc[mf], 0, 0, 0);
        }
    }

    // ---- stage 64 oc x 64 px tile to LDS ----
    const int pxl = wv * 16 + l15;                  // 0..63 block-local pixel
#pragma unroll
    for (int mf = 0; mf < 4; ++mf)
#pragma unroll
        for (int reg = 0; reg < 4; ++reg)
            Lds[(mf * 16 + quad * 4 + reg) * 68 + pxl] = acc[mf][reg];
    __syncthreads();   // single barrier; LDS read-only hereafter

    // ---- coalesced copy-out: 64 oc-rows x 64 px (16 float4 per row) ----
    const int pixb = blockIdx.x * 64 & (HW_ - 1);   // block-base pixel
#pragma unroll
    for (int it = 0; it < 4; ++it) {
        const int j4 = it * 256 + tid;
        const int r  = j4 >> 4;                     // oc 0..63
        const int c4 = j4 & 15;                     // float4 col
        float4 v;
        v.x = Lds[r * 68 + c4 * 4 + 0];
        v.y = Lds[r * 68 + c4 * 4 + 1];
        v.z = Lds[r * 68 + c4 * 4 + 2];
        v.w = Lds[r * 68 + c4 * 4 + 3];
        *(float4*)&out[((size_t)(b * C_ + r)) * HW_ + pixb + c4 * 4] = v;
    }
}

// ---------------------------------------------------------------------------
extern "C" void kernel_launch(void* const* d_in, const int* in_sizes, int n_in,
                              void* d_out, int out_size, void* d_ws, size_t ws_size,
                              hipStream_t stream)
{
    const float* x    = (const float*)d_in[0];
    const float* ef   = (const float*)d_in[1];
    const float* flow = (const float*)d_in[2];
    const float* w1   = (const float*)d_in[3];
    const float* b1   = (const float*)d_in[4];
    const float* w2   = (const float*)d_in[5];
    const float* b2   = (const float*)d_in[6];
    const float* w3   = (const float*)d_in[7];
    const float* b3   = (const float*)d_in[8];
    const float* wk   = (const float*)d_in[9];
    float* out = (float*)d_out;

    // Workspace (half slots):
    //   omh 14,155,776 | valh 18,874,368 | ef_p 4*B*HWP*32 = 4,326,400
    //   xg 2,097,152 | h1p 2*B*HWP*32 = 2,163,200 | h2p 2,163,200
    //   w1A 73,728 | w2A 36,864 | w3A 248,832 | wkA 36,864
    _Float16* omh  = (_Float16*)d_ws;
    _Float16* valh = omh + (size_t)B_ * OFFC_ * HW_;
    _Float16* ef_p = valh + (size_t)18 * B_ * HW_ * 32;
    _Float16* xg   = ef_p + (size_t)4 * B_ * HWP_ * 32;
    _Float16* h1p  = xg + (size_t)B_ * HW_ * 64;
    _Float16* h2p  = h1p + (size_t)2 * B_ * HWP_ * 32;
    _Float16* w1A  = h2p + (size_t)2 * B_ * HWP_ * 32;
    _Float16* w2A  = w1A + 64 * 128 * 9;
    _Float16* w3A  = w2A + 64 * 64 * 9;
    _Float16* wkA  = w3A + OFFC_ * 64 * 9;

    // Zero the padded buffers (borders must be 0; interiors overwritten).
    hipMemsetAsync(ef_p, 0, (size_t)4 * B_ * HWP_ * 32 * 2, stream);
    hipMemsetAsync(h1p, 0, (size_t)2 * B_ * HWP_ * 32 * 2, stream);
    hipMemsetAsync(h2p, 0, (size_t)2 * B_ * HWP_ * 32 * 2, stream);

    prep_wA_k<64, 128><<<dim3((64 * 128 * 9 + 255) / 256), 256, 0, stream>>>(w1, w1A);
    prep_wA_k<64, 64><<<dim3((64 * 64 * 9 + 255) / 256), 256, 0, stream>>>(w2, w2A);
    prep_wA_k<OFFC_, 64><<<dim3((OFFC_ * 64 * 9 + 255) / 256), 256, 0, stream>>>(w3, w3A);
    prep_wkA_k<<<dim3((18 * 64 * 32 + 255) / 256), 256, 0, stream>>>(wk, wkA);
    nchw2slabpad_f16_k<128><<<dim3(HW_ / 256, B_), 256, 0, stream>>>(ef, ef_p);
    nchw2gx_f16_k<<<dim3(HW_ / 256, B_), 256, 0, stream>>>(x, xg);

    conv12_mfma_k<128><<<dim3(B_ * H_ * 2), 256, 0, stream>>>(ef_p, w1A, b1, h1p);
    conv12_mfma_k<64><<<dim3(B_ * H_ * 2), 256, 0, stream>>>(h1p, w2A, b2, h2p);
    conv3_mfma_k<<<dim3(B_ * H_, 3), 256, 0, stream>>>(h2p, w3A, b3, flow, omh);

    gather_k<<<dim3(HW_ / 256, B_ * KK_), 256, 0, stream>>>(xg, omh, valh);
    einsum_mfma_k<<<dim3(B_ * HW_ / 64), 256, 0, stream>>>(valh, wkA, out);
}

// Round 3
// 239.540 us; speedup vs baseline: 1.2180x; 1.0026x over previous
//
#include <hip/hip_runtime.h>
#include <math.h>

// Problem constants (fixed by setup_inputs)
constexpr int B_   = 2;
constexpr int C_   = 64;
constexpr int H_   = 128;
constexpr int W_   = 128;
constexpr int HW_  = H_ * W_;
constexpr int DG_  = 16;   // deformable groups
constexpr int KK_  = 9;    // 3x3 taps
constexpr int CG_  = 4;    // channels per group = C/DG
constexpr int OFFC_ = 3 * KK_ * DG_;  // 432
constexpr int R_   = C_ * KK_;        // 576 reduction length
constexpr int WP_  = 130;             // padded width/height
constexpr int HWP_ = WP_ * WP_;       // 16900 padded pixels

typedef _Float16 half8 __attribute__((ext_vector_type(8)));  // 8 f16 = 4 VGPR
typedef _Float16 half4 __attribute__((ext_vector_type(4)));  // 8-byte load/store
typedef float floatx4 __attribute__((ext_vector_type(4)));   // MFMA acc

// ---------------------------------------------------------------------------
// Generic MFMA A-operand prep: wA[(t*CH+h)*OC + oc][j] = f16(w[oc][(h*32+j)*9+t])
// ---------------------------------------------------------------------------
template <int OC, int CIN>
__global__ __launch_bounds__(256) void prep_wA_k(
    const float* __restrict__ w, _Float16* __restrict__ wA)
{
    constexpr int CH = CIN / 32;
    const int j = blockIdx.x * 256 + threadIdx.x;   // slab*OC*32 + oc*32 + jj
    if (j >= 9 * CH * OC * 32) return;
    const int slab = j / (OC * 32);
    const int rem  = j - slab * (OC * 32);
    const int oc   = rem >> 5;
    const int jj   = rem & 31;
    const int t    = slab / CH;
    const int h    = slab - t * CH;
    const int ic   = h * 32 + jj;
    wA[j] = (_Float16)w[(size_t)oc * (CIN * 9) + ic * 9 + t];
}

// ---------------------------------------------------------------------------
// Einsum A-operand prep: r = k*64 + gc (gc = g*4+c).  18 slabs of 32.
// ---------------------------------------------------------------------------
__global__ __launch_bounds__(256) void prep_wkA_k(
    const float* __restrict__ wk, _Float16* __restrict__ wkA)
{
    const int j = blockIdx.x * 256 + threadIdx.x;   // s*2048 + oc*32 + jj
    if (j >= 18 * 64 * 32) return;
    const int s   = j >> 11;
    const int rem = j & 2047;
    const int oc  = rem >> 5;
    const int jj  = rem & 31;
    const int k   = s >> 1;
    const int gc  = (s & 1) * 32 + jj;
    wkA[j] = (_Float16)wk[(size_t)oc * R_ + gc * 9 + k];
}

// ---------------------------------------------------------------------------
// NCHW fp32 -> PADDED slab-split f16: out[(c/32)*B + b][y+1][x+1][32].
// Borders pre-zeroed by hipMemsetAsync -> conv loads need no predication.
// ---------------------------------------------------------------------------
template <int CC>
__global__ __launch_bounds__(256) void nchw2slabpad_f16_k(
    const float* __restrict__ in, _Float16* __restrict__ outh)
{
    const int pix = blockIdx.x * 256 + threadIdx.x;
    const int b   = blockIdx.y;
    const int yp  = pix >> 7;
    const int xp  = pix & (W_ - 1);
    const float* ib = in + (size_t)b * CC * HW_ + pix;
#pragma unroll
    for (int c0 = 0; c0 < CC; c0 += 8) {
        half8 v;
#pragma unroll
        for (int j = 0; j < 8; ++j)
            v[j] = (_Float16)ib[(size_t)(c0 + j) * HW_];
        const int slab = c0 >> 5;
        *(half8*)&outh[((size_t)(slab * B_ + b) * HWP_
                        + (size_t)(yp + 1) * WP_ + (xp + 1)) * 32 + (c0 & 31)] = v;
    }
}

// ---------------------------------------------------------------------------
// NCHW fp32 -> per-group planes f16: xg[((b*DG+g)*HW + pix)*4 + c].
// ---------------------------------------------------------------------------
__global__ __launch_bounds__(256) void nchw2gx_f16_k(
    const float* __restrict__ in, _Float16* __restrict__ outh)
{
    const int pix = blockIdx.x * 256 + threadIdx.x;
    const int b   = blockIdx.y;
    const float* ib = in + (size_t)b * C_ * HW_ + pix;
#pragma unroll
    for (int g = 0; g < DG_; ++g) {
        half4 v;
#pragma unroll
        for (int c = 0; c < 4; ++c)
            v[c] = (_Float16)ib[(size_t)(g * 4 + c) * HW_];
        *(half4*)&outh[((size_t)(b * DG_ + g) * HW_ + pix) * 4] = v;
    }
}

// ---------------------------------------------------------------------------
// Conv1/conv2 (CIN -> 64) via f16 MFMA, padded input -> UNCONDITIONAL loads.
// Wave tile = 64 oc x 16 px (mf=4).
// v3: explicit 1-step register double-buffer of the 5 fragments per K-step
// (issue step k+1's loads before step k's MFMAs) + launch_bounds(,1) so the
// allocator has registers for it. Kills the load->wait->mfma serialization.
// ---------------------------------------------------------------------------
template <int CIN>
__global__ __launch_bounds__(256, 1) void conv12_mfma_k(
    const _Float16* __restrict__ inp, const _Float16* __restrict__ wA,
    const float* __restrict__ bias, _Float16* __restrict__ outp)
{
    constexpr int CH = CIN / 32;
    constexpr int NS = 9 * CH;            // K-steps
    const int tid  = threadIdx.x;
    const int lane = tid & 63;
    const int wv   = tid >> 6;
    const int l15  = lane & 15;
    const int quad = lane >> 4;

    const int zx   = blockIdx.x;          // (b*H + y)*2 + half64
    const int row  = zx >> 1;
    const int b    = row >> 7;
    const int y    = row & 127;
    const int px0  = (zx & 1) * 64 + wv * 16;

    floatx4 acc[4];
#pragma unroll
    for (int mf = 0; mf < 4; ++mf)
        acc[mf] = (floatx4){0.f, 0.f, 0.f, 0.f};

    half8 Af[2][4];
    half8 Bf[2];

    // prologue: load step 0 (t=0 -> dy=0, dx=0; h=0)
    {
        Bf[0] = *(const half8*)&inp[
            ((size_t)(0 * B_ + b) * HWP_ + (size_t)(y + 0) * WP_
             + (px0 + l15 + 0)) * 32 + quad * 8];
        const _Float16* ap = wA + ((size_t)0 * 64 + l15) * 32 + quad * 8;
#pragma unroll
        for (int mf = 0; mf < 4; ++mf)
            Af[0][mf] = *(const half8*)&ap[(size_t)(mf * 16) * 32];
    }

#pragma unroll
    for (int ks = 0; ks < NS; ++ks) {
        const int cur = ks & 1, nxt = cur ^ 1;
        if (ks < NS - 1) {
            const int ks1 = ks + 1;
            const int t = ks1 / CH, h = ks1 % CH;
            const int dy = t / 3, dx = t % 3;
            Bf[nxt] = *(const half8*)&inp[
                ((size_t)(h * B_ + b) * HWP_ + (size_t)(y + dy) * WP_
                 + (px0 + l15 + dx)) * 32 + quad * 8];
            const _Float16* ap = wA + ((size_t)ks1 * 64 + l15) * 32 + quad * 8;
#pragma unroll
            for (int mf = 0; mf < 4; ++mf)
                Af[nxt][mf] = *(const half8*)&ap[(size_t)(mf * 16) * 32];
        }
#pragma unroll
        for (int mf = 0; mf < 4; ++mf)
            acc[mf] = __builtin_amdgcn_mfma_f32_16x16x32_f16(
                Af[cur][mf], Bf[cur], acc[mf], 0, 0, 0);
    }

    // epilogue: leaky ReLU, padded slab-split f16 store (8 B/lane x 4 tiles)
#pragma unroll
    for (int mf = 0; mf < 4; ++mf) {
        const int oc4 = mf * 16 + quad * 4;        // first of 4 output chans
        const float4 b4 = *(const float4*)&bias[oc4];
        half4 v4;
#pragma unroll
        for (int reg = 0; reg < 4; ++reg) {
            float r = acc[mf][reg] + ((const float*)&b4)[reg];
            r = (r >= 0.f) ? r : 0.1f * r;
            v4[reg] = (_Float16)r;
        }
        *(half4*)&outp[((size_t)((oc4 >> 5) * B_ + b) * HWP_
                        + (size_t)(y + 1) * WP_ + (px0 + l15 + 1)) * 32 + (oc4 & 31)] = v4;
    }
}

// ---------------------------------------------------------------------------
// Conv3 via f16 MFMA implicit GEMM. Wave tile = 144 oc x 32 px (mf=9).
// v3: explicit 1-step register double-buffer of all 11 fragments per K-step
// (9 A + 2 B) + launch_bounds(,1). Round-2 counters showed ~2250 stall
// cycles per K-step at VGPR_Count=80: the allocator had no room to hoist,
// so loads were issued serially with full-latency waits.
// ---------------------------------------------------------------------------
__global__ __launch_bounds__(256, 1) void conv3_mfma_k(
    const _Float16* __restrict__ h2p, const _Float16* __restrict__ w3A,
    const float* __restrict__ bias, const float* __restrict__ flow,
    _Float16* __restrict__ omh)
{
    __shared__ __align__(16) _Float16 Lds[144 * 132];   // 38016 B

    const int tid  = threadIdx.x;
    const int lane = tid & 63;
    const int wv   = tid >> 6;       // wave id 0..3
    const int l15  = lane & 15;
    const int quad = lane >> 4;

    const int row = blockIdx.x;      // b*128 + y
    const int b   = row >> 7;
    const int y   = row & 127;
    const int m0  = blockIdx.y * 144; // oc tile base (0,144,288)
    const int px0 = wv * 32;

    floatx4 acc[9][2];
#pragma unroll
    for (int mf = 0; mf < 9; ++mf)
#pragma unroll
        for (int nf = 0; nf < 2; ++nf)
            acc[mf][nf] = (floatx4){0.f, 0.f, 0.f, 0.f};

    half8 Af[2][9];
    half8 Bf[2][2];

    // prologue: load step 0 (ks = t*2+h = 0 -> t=0 (dy=0,dx=0), h=0)
    {
#pragma unroll
        for (int nf = 0; nf < 2; ++nf)
            Bf[0][nf] = *(const half8*)&h2p[
                ((size_t)(0 * B_ + b) * HWP_ + (size_t)(y + 0) * WP_
                 + (px0 + nf * 16 + l15 + 0)) * 32 + quad * 8];
        const _Float16* wbase = w3A + ((size_t)0 * OFFC_ + m0 + l15) * 32 + quad * 8;
#pragma unroll
        for (int mf = 0; mf < 9; ++mf)
            Af[0][mf] = *(const half8*)&wbase[(size_t)(mf * 16) * 32];
    }

#pragma unroll
    for (int ks = 0; ks < 18; ++ks) {           // ks = t*2 + h
        const int cur = ks & 1, nxt = cur ^ 1;
        if (ks < 17) {
            const int ks1 = ks + 1;
            const int t = ks1 >> 1, h = ks1 & 1;
            const int dy = t / 3, dx = t % 3;
#pragma unroll
            for (int nf = 0; nf < 2; ++nf)
                Bf[nxt][nf] = *(const half8*)&h2p[
                    ((size_t)(h * B_ + b) * HWP_ + (size_t)(y + dy) * WP_
                     + (px0 + nf * 16 + l15 + dx)) * 32 + quad * 8];
            const _Float16* wbase = w3A + ((size_t)ks1 * OFFC_ + m0 + l15) * 32 + quad * 8;
#pragma unroll
            for (int mf = 0; mf < 9; ++mf)
                Af[nxt][mf] = *(const half8*)&wbase[(size_t)(mf * 16) * 32];
        }
#pragma unroll
        for (int mf = 0; mf < 9; ++mf)
#pragma unroll
            for (int nf = 0; nf < 2; ++nf)
                acc[mf][nf] = __builtin_amdgcn_mfma_f32_16x16x32_f16(
                    Af[cur][mf], Bf[cur][nf], acc[mf][nf], 0, 0, 0);
    }

    // ---- transform + stage to LDS (f16, 144 rows x 128 px, pad to 132) ----
    const bool is_off = (blockIdx.y < 2);     // block-uniform channel class
    float flY[2], flX[2];
#pragma unroll
    for (int nf = 0; nf < 2; ++nf) {
        const int px = px0 + nf * 16 + l15;
        if (is_off) {
            flY[nf] = flow[(size_t)(b * 2 + 1) * HW_ + y * W_ + px]; // slot 0 (y)
            flX[nf] = flow[(size_t)(b * 2 + 0) * HW_ + y * W_ + px]; // slot 1 (x)
        }
    }
#pragma unroll
    for (int mf = 0; mf < 9; ++mf) {
        const float4 b4 = *(const float4*)&bias[m0 + mf * 16 + quad * 4];
#pragma unroll
        for (int nf = 0; nf < 2; ++nf) {
            const int px = px0 + nf * 16 + l15;
#pragma unroll
            for (int reg = 0; reg < 4; ++reg) {
                const int ocl = mf * 16 + quad * 4 + reg;   // 0..143
                float val = acc[mf][nf][reg] + ((const float*)&b4)[reg];
                if (is_off) {                       // offset channels
                    const int slot = reg & 1;       // 0 = y, 1 = x
                    const float fl = slot ? flX[nf] : flY[nf];
                    const float e = __expf(2.f * val);      // tanh via exp
                    val = 10.f * (1.f - __fdividef(2.f, e + 1.f)) + fl;
                } else {                            // mask channels: sigmoid
                    val = __fdividef(1.f, 1.f + __expf(-val));
                }
                Lds[ocl * 132 + px] = (_Float16)val;
            }
        }
    }
    __syncthreads();   // single barrier; LDS read-only hereafter

    // ---- contiguous f16 copy-out: 144 plane-rows x 128 px ----
#pragma unroll
    for (int it = 0; it < 18; ++it) {
        const int j4 = it * 256 + tid;
        const int r  = j4 >> 5;          // 0..143
        const int c4 = j4 & 31;          // half4 col
        const int oc = m0 + r;
        int g, k, slot;
        if (oc < 2 * DG_ * KK_) {
            g = oc / 18;
            const int rem = oc - g * 18;
            k = rem >> 1;
            slot = rem & 1;
        } else {
            const int c = oc - 2 * DG_ * KK_;
            g = c / 9;
            k = c - g * 9;
            slot = 2;
        }
        const half4 hv = *(const half4*)&Lds[r * 132 + c4 * 4];
        *(half4*)&omh[((size_t)((b * DG_ * KK_ + g * KK_ + k) * 3 + slot)) * HW_
                      + y * W_ + c4 * 4] = hv;
    }
}

// ---------------------------------------------------------------------------
// Phase A: bilinear gather, PIXEL-MAJOR lanes. Thread = one pixel for a
// fixed (b,k); loops g=0..15 in registers.
// ---------------------------------------------------------------------------
__global__ __launch_bounds__(256) void gather_k(
    const _Float16* __restrict__ xg, const _Float16* __restrict__ omh,
    _Float16* __restrict__ valh)
{
    const int tid = threadIdx.x;
    const int pix = blockIdx.x * 256 + tid;
    const int zy  = blockIdx.y;               // b*9 + k
    const int b   = zy / KK_;
    const int k   = zy - b * KK_;
    const int yp  = pix >> 7;
    const int xp  = pix & (W_ - 1);
    const float fy = (float)(yp + (k / 3) - 1);
    const float fx = (float)(xp + (k % 3) - 1);

    half4 rec[16];
#pragma unroll
    for (int g = 0; g < DG_; ++g) {
        const size_t obase = ((size_t)((b * DG_ + g) * KK_ + k) * 3) * HW_ + pix;
        const float oy = (float)omh[obase];
        const float ox = (float)omh[obase + HW_];
        const float m  = (float)omh[obase + 2 * HW_];

        const float py = fy + oy;
        const float px = fx + ox;
        const float y0f = floorf(py);
        const float x0f = floorf(px);
        const float wy = py - y0f;
        const float wx = px - x0f;
        const int y0 = (int)y0f, x0 = (int)x0f;
        const int y1 = y0 + 1,  x1 = x0 + 1;
        const bool vy0 = ((unsigned)y0 < (unsigned)H_);
        const bool vy1 = ((unsigned)y1 < (unsigned)H_);
        const bool vx0 = ((unsigned)x0 < (unsigned)W_);
        const bool vx1 = ((unsigned)x1 < (unsigned)W_);
        const float w00 = vy0 && vx0 ? (1.f - wy) * (1.f - wx) : 0.f;
        const float w01 = vy0 && vx1 ? (1.f - wy) * wx         : 0.f;
        const float w10 = vy1 && vx0 ? wy * (1.f - wx)         : 0.f;
        const float w11 = vy1 && vx1 ? wy * wx                 : 0.f;
        const int i00 = (vy0 && vx0) ? y0 * W_ + x0 : 0;
        const int i01 = (vy0 && vx1) ? y0 * W_ + x1 : 0;
        const int i10 = (vy1 && vx0) ? y1 * W_ + x0 : 0;
        const int i11 = (vy1 && vx1) ? y1 * W_ + x1 : 0;

        const _Float16* xb = xg + (size_t)(b * DG_ + g) * HW_ * 4;
        const half4 p00 = *(const half4*)&xb[(size_t)i00 * 4];
        const half4 p01 = *(const half4*)&xb[(size_t)i01 * 4];
        const half4 p10 = *(const half4*)&xb[(size_t)i10 * 4];
        const half4 p11 = *(const half4*)&xb[(size_t)i11 * 4];

        half4 v4;
#pragma unroll
        for (int c = 0; c < CG_; ++c) {
            float v = w00 * (float)p00[c] + w01 * (float)p01[c]
                    + w10 * (float)p10[c] + w11 * (float)p11[c];
            v4[c] = (_Float16)(v * m);
        }
        rec[g] = v4;
    }

    // write slabs s = 2k (g 0..7) and 2k+1 (g 8..15): 64 B each, contiguous
    _Float16* r0 = &valh[((size_t)((2 * k) * B_ + b) * HW_ + pix) * 32];
    _Float16* r1 = &valh[((size_t)((2 * k + 1) * B_ + b) * HW_ + pix) * 32];
#pragma unroll
    for (int j = 0; j < 4; ++j) {
        half8 w0, w1;
#pragma unroll
        for (int c = 0; c < 4; ++c) {
            w0[c]     = rec[2 * j][c];
            w0[c + 4] = rec[2 * j + 1][c];
            w1[c]     = rec[8 + 2 * j][c];
            w1[c + 4] = rec[9 + 2 * j][c];
        }
        *(half8*)&r0[j * 8] = w0;
        *(half8*)&r1[j * 8] = w1;
    }
}

// ---------------------------------------------------------------------------
// Phase B: einsum via f16 MFMA, SINGLE PASS. Wave = 16 px x 64 oc (mf=4).
// v3: explicit 1-step register double-buffer of the 5 fragments per step.
// ---------------------------------------------------------------------------
__global__ __launch_bounds__(256, 1) void einsum_mfma_k(
    const _Float16* __restrict__ valh, const _Float16* __restrict__ wkA,
    float* __restrict__ out)
{
    __shared__ __align__(16) float Lds[64 * 68];   // 64 oc x 64 px (pad 68)

    const int tid  = threadIdx.x;
    const int lane = tid & 63;
    const int wv   = tid >> 6;
    const int l15  = lane & 15;
    const int quad = lane >> 4;

    const int pixg0 = blockIdx.x * 64 + wv * 16;    // global pixel (b*HW+pix)
    const int b     = pixg0 >> 14;
    const int pix0  = pixg0 & (HW_ - 1);

    floatx4 acc[4];
#pragma unroll
    for (int mf = 0; mf < 4; ++mf)
        acc[mf] = (floatx4){0.f, 0.f, 0.f, 0.f};

    half8 Af[2][4];
    half8 Bf[2];

    // prologue: load step 0
    {
        Bf[0] = *(const half8*)&valh[
            ((size_t)(0 * B_ + b) * HW_ + pix0 + l15) * 32 + quad * 8];
        const _Float16* ap = wkA;
#pragma unroll
        for (int mf = 0; mf < 4; ++mf)
            Af[0][mf] = *(const half8*)&ap[(mf * 16 + l15) * 32 + quad * 8];
    }

#pragma unroll
    for (int s = 0; s < 18; ++s) {
        const int cur = s & 1, nxt = cur ^ 1;
        if (s < 17) {
            const int s1 = s + 1;
            Bf[nxt] = *(const half8*)&valh[
                ((size_t)(s1 * B_ + b) * HW_ + pix0 + l15) * 32 + quad * 8];
            const _Float16* ap = wkA + (size_t)s1 * 64 * 32;
#pragma unroll
            for (int mf = 0; mf < 4; ++mf)
                Af[nxt][mf] = *(const half8*)&ap[(mf * 16 + l15) * 32 + quad * 8];
        }
#pragma unroll
        for (int mf = 0; mf < 4; ++mf)
            acc[mf] = __builtin_amdgcn_mfma_f32_16x16x32_f16(
                Af[cur][mf], Bf[cur], acc[mf], 0, 0, 0);
    }

    // ---- stage 64 oc x 64 px tile to LDS ----
    const int pxl = wv * 16 + l15;                  // 0..63 block-local pixel
#pragma unroll
    for (int mf = 0; mf < 4; ++mf)
#pragma unroll
        for (int reg = 0; reg < 4; ++reg)
            Lds[(mf * 16 + quad * 4 + reg) * 68 + pxl] = acc[mf][reg];
    __syncthreads();   // single barrier; LDS read-only hereafter

    // ---- coalesced copy-out: 64 oc-rows x 64 px (16 float4 per row) ----
    const int pixb = blockIdx.x * 64 & (HW_ - 1);   // block-base pixel
#pragma unroll
    for (int it = 0; it < 4; ++it) {
        const int j4 = it * 256 + tid;
        const int r  = j4 >> 4;                     // oc 0..63
        const int c4 = j4 & 15;                     // float4 col
        float4 v;
        v.x = Lds[r * 68 + c4 * 4 + 0];
        v.y = Lds[r * 68 + c4 * 4 + 1];
        v.z = Lds[r * 68 + c4 * 4 + 2];
        v.w = Lds[r * 68 + c4 * 4 + 3];
        *(float4*)&out[((size_t)(b * C_ + r)) * HW_ + pixb + c4 * 4] = v;
    }
}

// ---------------------------------------------------------------------------
extern "C" void kernel_launch(void* const* d_in, const int* in_sizes, int n_in,
                              void* d_out, int out_size, void* d_ws, size_t ws_size,
                              hipStream_t stream)
{
    const float* x    = (const float*)d_in[0];
    const float* ef   = (const float*)d_in[1];
    const float* flow = (const float*)d_in[2];
    const float* w1   = (const float*)d_in[3];
    const float* b1   = (const float*)d_in[4];
    const float* w2   = (const float*)d_in[5];
    const float* b2   = (const float*)d_in[6];
    const float* w3   = (const float*)d_in[7];
    const float* b3   = (const float*)d_in[8];
    const float* wk   = (const float*)d_in[9];
    float* out = (float*)d_out;

    // Workspace (half slots):
    //   omh 14,155,776 | valh 18,874,368 | ef_p 4*B*HWP*32 = 4,326,400
    //   xg 2,097,152 | h1p 2*B*HWP*32 = 2,163,200 | h2p 2,163,200
    //   w1A 73,728 | w2A 36,864 | w3A 248,832 | wkA 36,864
    _Float16* omh  = (_Float16*)d_ws;
    _Float16* valh = omh + (size_t)B_ * OFFC_ * HW_;
    _Float16* ef_p = valh + (size_t)18 * B_ * HW_ * 32;
    _Float16* xg   = ef_p + (size_t)4 * B_ * HWP_ * 32;
    _Float16* h1p  = xg + (size_t)B_ * HW_ * 64;
    _Float16* h2p  = h1p + (size_t)2 * B_ * HWP_ * 32;
    _Float16* w1A  = h2p + (size_t)2 * B_ * HWP_ * 32;
    _Float16* w2A  = w1A + 64 * 128 * 9;
    _Float16* w3A  = w2A + 64 * 64 * 9;
    _Float16* wkA  = w3A + OFFC_ * 64 * 9;

    // Zero the padded buffers (borders must be 0; interiors overwritten).
    hipMemsetAsync(ef_p, 0, (size_t)4 * B_ * HWP_ * 32 * 2, stream);
    hipMemsetAsync(h1p, 0, (size_t)2 * B_ * HWP_ * 32 * 2, stream);
    hipMemsetAsync(h2p, 0, (size_t)2 * B_ * HWP_ * 32 * 2, stream);

    prep_wA_k<64, 128><<<dim3((64 * 128 * 9 + 255) / 256), 256, 0, stream>>>(w1, w1A);
    prep_wA_k<64, 64><<<dim3((64 * 64 * 9 + 255) / 256), 256, 0, stream>>>(w2, w2A);
    prep_wA_k<OFFC_, 64><<<dim3((OFFC_ * 64 * 9 + 255) / 256), 256, 0, stream>>>(w3, w3A);
    prep_wkA_k<<<dim3((18 * 64 * 32 + 255) / 256), 256, 0, stream>>>(wk, wkA);
    nchw2slabpad_f16_k<128><<<dim3(HW_ / 256, B_), 256, 0, stream>>>(ef, ef_p);
    nchw2gx_f16_k<<<dim3(HW_ / 256, B_), 256, 0, stream>>>(x, xg);

    conv12_mfma_k<128><<<dim3(B_ * H_ * 2), 256, 0, stream>>>(ef_p, w1A, b1, h1p);
    conv12_mfma_k<64><<<dim3(B_ * H_ * 2), 256, 0, stream>>>(h1p, w2A, b2, h2p);
    conv3_mfma_k<<<dim3(B_ * H_, 3), 256, 0, stream>>>(h2p, w3A, b3, flow, omh);

    gather_k<<<dim3(HW_ / 256, B_ * KK_), 256, 0, stream>>>(xg, omh, valh);
    einsum_mfma_k<<<dim3(B_ * HW_ / 64), 256, 0, stream>>>(valh, wkA, out);
}

// Round 5
// 204.761 us; speedup vs baseline: 1.4249x; 1.1699x over previous
//
#include <hip/hip_runtime.h>
#include <math.h>

// Problem constants (fixed by setup_inputs)
constexpr int B_   = 2;
constexpr int C_   = 64;
constexpr int H_   = 128;
constexpr int W_   = 128;
constexpr int HW_  = H_ * W_;
constexpr int DG_  = 16;   // deformable groups
constexpr int KK_  = 9;    // 3x3 taps
constexpr int CG_  = 4;    // channels per group = C/DG
constexpr int OFFC_ = 3 * KK_ * DG_;  // 432
constexpr int R_   = C_ * KK_;        // 576 reduction length
constexpr int WP_  = 130;             // padded width/height
constexpr int HWP_ = WP_ * WP_;       // 16900 padded pixels

typedef _Float16 half8 __attribute__((ext_vector_type(8)));  // 8 f16 = 4 VGPR
typedef _Float16 half4 __attribute__((ext_vector_type(4)));  // 8-byte load/store
typedef float floatx4 __attribute__((ext_vector_type(4)));   // MFMA acc

// Async global->LDS DMA, 16 B per lane. LDS dest is wave-uniform base +
// lane*16 (m104); every call site passes exactly that shape.
__device__ __forceinline__ void gl_lds16(const _Float16* g, _Float16* l)
{
    __builtin_amdgcn_global_load_lds(
        (const __attribute__((address_space(1))) void*)g,
        (__attribute__((address_space(3))) void*)l, 16, 0, 0);
}

// Fragment-major A staging: LDS chunk c (16 B) holds the data fragment
// (mf = c>>6) needs at lane (c&63): global f16 index within the K-slice.
// Reader then does afr[mf] = lds[base + lane*16 + mf*1024] -> addresses
// linear in lane -> conflict-free ds_read_b128.
__device__ __forceinline__ int afrag_src(int c)
{
    const int cmf = c >> 6, cq = (c >> 4) & 3, cl = c & 15;
    return (cmf * 16 + cl) * 32 + cq * 8;
}

// ---------------------------------------------------------------------------
// Generic MFMA A-operand prep: wA[(t*CH+h)*OC + oc][j] = f16(w[oc][(h*32+j)*9+t])
// ---------------------------------------------------------------------------
template <int OC, int CIN>
__global__ __launch_bounds__(256) void prep_wA_k(
    const float* __restrict__ w, _Float16* __restrict__ wA)
{
    constexpr int CH = CIN / 32;
    const int j = blockIdx.x * 256 + threadIdx.x;   // slab*OC*32 + oc*32 + jj
    if (j >= 9 * CH * OC * 32) return;
    const int slab = j / (OC * 32);
    const int rem  = j - slab * (OC * 32);
    const int oc   = rem >> 5;
    const int jj   = rem & 31;
    const int t    = slab / CH;
    const int h    = slab - t * CH;
    const int ic   = h * 32 + jj;
    wA[j] = (_Float16)w[(size_t)oc * (CIN * 9) + ic * 9 + t];
}

// ---------------------------------------------------------------------------
// Einsum A-operand prep: r = k*64 + gc (gc = g*4+c).  18 slabs of 32.
// ---------------------------------------------------------------------------
__global__ __launch_bounds__(256) void prep_wkA_k(
    const float* __restrict__ wk, _Float16* __restrict__ wkA)
{
    const int j = blockIdx.x * 256 + threadIdx.x;   // s*2048 + oc*32 + jj
    if (j >= 18 * 64 * 32) return;
    const int s   = j >> 11;
    const int rem = j & 2047;
    const int oc  = rem >> 5;
    const int jj  = rem & 31;
    const int k   = s >> 1;
    const int gc  = (s & 1) * 32 + jj;
    wkA[j] = (_Float16)wk[(size_t)oc * R_ + gc * 9 + k];
}

// ---------------------------------------------------------------------------
// NCHW fp32 -> PADDED slab-split f16: out[(c/32)*B + b][y+1][x+1][32].
// ---------------------------------------------------------------------------
template <int CC>
__global__ __launch_bounds__(256) void nchw2slabpad_f16_k(
    const float* __restrict__ in, _Float16* __restrict__ outh)
{
    const int pix = blockIdx.x * 256 + threadIdx.x;
    const int b   = blockIdx.y;
    const int yp  = pix >> 7;
    const int xp  = pix & (W_ - 1);
    const float* ib = in + (size_t)b * CC * HW_ + pix;
#pragma unroll
    for (int c0 = 0; c0 < CC; c0 += 8) {
        half8 v;
#pragma unroll
        for (int j = 0; j < 8; ++j)
            v[j] = (_Float16)ib[(size_t)(c0 + j) * HW_];
        const int slab = c0 >> 5;
        *(half8*)&outh[((size_t)(slab * B_ + b) * HWP_
                        + (size_t)(yp + 1) * WP_ + (xp + 1)) * 32 + (c0 & 31)] = v;
    }
}

// ---------------------------------------------------------------------------
// NCHW fp32 -> per-group planes f16: xg[((b*DG+g)*HW + pix)*4 + c].
// ---------------------------------------------------------------------------
__global__ __launch_bounds__(256) void nchw2gx_f16_k(
    const float* __restrict__ in, _Float16* __restrict__ outh)
{
    const int pix = blockIdx.x * 256 + threadIdx.x;
    const int b   = blockIdx.y;
    const float* ib = in + (size_t)b * C_ * HW_ + pix;
#pragma unroll
    for (int g = 0; g < DG_; ++g) {
        half4 v;
#pragma unroll
        for (int c = 0; c < 4; ++c)
            v[c] = (_Float16)ib[(size_t)(g * 4 + c) * HW_];
        *(half4*)&outh[((size_t)(b * DG_ + g) * HW_ + pix) * 4] = v;
    }
}

// ---------------------------------------------------------------------------
// Conv1/conv2 (CIN -> 64) via f16 MFMA. Wave tile = 64 oc x 16 px (mf=4).
// v4: 2-phase LDS pipeline. A (shared by all 4 waves) staged per K-step via
// global_load_lds double-buffer in fragment-major layout; B prefetched to
// registers one step ahead; __syncthreads() per step drains the DMA.
// ---------------------------------------------------------------------------
template <int CIN>
__global__ __launch_bounds__(256, 2) void conv12_mfma_k(
    const _Float16* __restrict__ inp, const _Float16* __restrict__ wA,
    const float* __restrict__ bias, _Float16* __restrict__ outp)
{
    constexpr int CH = CIN / 32;
    constexpr int NS = 9 * CH;            // K-steps
    __shared__ __align__(16) _Float16 Asm[2 * 2048];   // 2 x 4096 B

    const int tid  = threadIdx.x;
    const int lane = tid & 63;
    const int wv   = tid >> 6;
    const int l15  = lane & 15;
    const int quad = lane >> 4;

    const int zx   = blockIdx.x;          // (b*H + y)*2 + half64
    const int row  = zx >> 1;
    const int b    = row >> 7;
    const int y    = row & 127;
    const int px0  = (zx & 1) * 64 + wv * 16;

    const int sA = afrag_src(tid);        // global f16 offset for my chunk

    floatx4 acc[4];
#pragma unroll
    for (int mf = 0; mf < 4; ++mf)
        acc[mf] = (floatx4){0.f, 0.f, 0.f, 0.f};

    half8 Bf[2];

    // prologue: stage A step 0, load B step 0
    gl_lds16(wA + sA, Asm + tid * 8);
    Bf[0] = *(const half8*)&inp[
        ((size_t)(0 * B_ + b) * HWP_ + (size_t)(y + 0) * WP_
         + (px0 + l15 + 0)) * 32 + quad * 8];
    __syncthreads();

#pragma unroll
    for (int ks = 0; ks < NS; ++ks) {
        const int cur = ks & 1, nxt = cur ^ 1;
        if (ks < NS - 1) {
            const int ks1 = ks + 1;
            const int t = ks1 / CH, h = ks1 % CH;
            const int dy = t / 3, dx = t % 3;
            gl_lds16(wA + (size_t)ks1 * 2048 + sA, Asm + nxt * 2048 + tid * 8);
            Bf[nxt] = *(const half8*)&inp[
                ((size_t)(h * B_ + b) * HWP_ + (size_t)(y + dy) * WP_
                 + (px0 + l15 + dx)) * 32 + quad * 8];
        }
        const _Float16* abase = Asm + cur * 2048 + lane * 8;
#pragma unroll
        for (int mf = 0; mf < 4; ++mf) {
            const half8 afr = *(const half8*)&abase[mf * 512];
            acc[mf] = __builtin_amdgcn_mfma_f32_16x16x32_f16(afr, Bf[cur], acc[mf], 0, 0, 0);
        }
        __syncthreads();   // drains vmcnt: next step's A (and B) landed
    }

    // epilogue: leaky ReLU, padded slab-split f16 store (8 B/lane x 4 tiles)
#pragma unroll
    for (int mf = 0; mf < 4; ++mf) {
        const int oc4 = mf * 16 + quad * 4;        // first of 4 output chans
        const float4 b4 = *(const float4*)&bias[oc4];
        half4 v4;
#pragma unroll
        for (int reg = 0; reg < 4; ++reg) {
            float r = acc[mf][reg] + ((const float*)&b4)[reg];
            r = (r >= 0.f) ? r : 0.1f * r;
            v4[reg] = (_Float16)r;
        }
        *(half4*)&outp[((size_t)((oc4 >> 5) * B_ + b) * HWP_
                        + (size_t)(y + 1) * WP_ + (px0 + l15 + 1)) * 32 + (oc4 & 31)] = v4;
    }
}

// ---------------------------------------------------------------------------
// Conv3 via f16 MFMA implicit GEMM. Wave tile = 144 oc x 32 px (mf=9).
// v4: 2-phase LDS pipeline. Per K-step A slice = 144x32 f16 = 9216 B staged
// by DMA (2.25 rounds: 2 all-wave + 1 wave-0), fragment-major; B (2 frags)
// prefetched to regs one step ahead. Staging LDS (18.4 KB) aliases the
// epilogue LDS (38 KB) -- the in-loop trailing barrier separates them.
// ---------------------------------------------------------------------------
__global__ __launch_bounds__(256, 2) void conv3_mfma_k(
    const _Float16* __restrict__ h2p, const _Float16* __restrict__ w3A,
    const float* __restrict__ bias, const float* __restrict__ flow,
    _Float16* __restrict__ omh)
{
    __shared__ __align__(16) _Float16 Smem[144 * 132];   // 38016 B (union)
    _Float16* Asm = Smem;                                // A dbuf: 2 x 4608 f16
    _Float16* Lds = Smem;                                // epilogue view

    const int tid  = threadIdx.x;
    const int lane = tid & 63;
    const int wv   = tid >> 6;       // wave id 0..3
    const int l15  = lane & 15;
    const int quad = lane >> 4;

    const int row = blockIdx.x;      // b*128 + y
    const int b   = row >> 7;
    const int y   = row & 127;
    const int m0  = blockIdx.y * 144; // oc tile base (0,144,288)
    const int px0 = wv * 32;

    const int c0 = wv * 64 + lane;   // staging chunks
    const int c1 = 256 + c0;
    const int c2 = 512 + lane;       // wave 0 only
    const int s0 = afrag_src(c0), s1 = afrag_src(c1), s2 = afrag_src(c2);

    floatx4 acc[9][2];
#pragma unroll
    for (int mf = 0; mf < 9; ++mf)
#pragma unroll
        for (int nf = 0; nf < 2; ++nf)
            acc[mf][nf] = (floatx4){0.f, 0.f, 0.f, 0.f};

    half8 Bf[2][2];

    // prologue: stage A step 0, load B step 0 (ks=0 -> t=0 (dy=dx=0), h=0)
    {
        const _Float16* asrc = w3A + (size_t)m0 * 32;
        gl_lds16(asrc + s0, Asm + c0 * 8);
        gl_lds16(asrc + s1, Asm + c1 * 8);
        if (wv == 0) gl_lds16(asrc + s2, Asm + c2 * 8);
#pragma unroll
        for (int nf = 0; nf < 2; ++nf)
            Bf[0][nf] = *(const half8*)&h2p[
                ((size_t)(0 * B_ + b) * HWP_ + (size_t)(y + 0) * WP_
                 + (px0 + nf * 16 + l15 + 0)) * 32 + quad * 8];
    }
    __syncthreads();

#pragma unroll
    for (int ks = 0; ks < 18; ++ks) {           // ks = t*2 + h
        const int cur = ks & 1, nxt = cur ^ 1;
        if (ks < 17) {
            const int ks1 = ks + 1;
            const int t = ks1 >> 1, h = ks1 & 1;
            const int dy = t / 3, dx = t % 3;
            const _Float16* asrc = w3A + ((size_t)ks1 * OFFC_ + m0) * 32;
            _Float16* adst = Asm + nxt * 4608;
            gl_lds16(asrc + s0, adst + c0 * 8);
            gl_lds16(asrc + s1, adst + c1 * 8);
            if (wv == 0) gl_lds16(asrc + s2, adst + c2 * 8);
#pragma unroll
            for (int nf = 0; nf < 2; ++nf)
                Bf[nxt][nf] = *(const half8*)&h2p[
                    ((size_t)(h * B_ + b) * HWP_ + (size_t)(y + dy) * WP_
                     + (px0 + nf * 16 + l15 + dx)) * 32 + quad * 8];
        }
        const _Float16* abase = Asm + cur * 4608 + lane * 8;
#pragma unroll
        for (int mf = 0; mf < 9; ++mf) {
            const half8 afr = *(const half8*)&abase[mf * 512];
            acc[mf][0] = __builtin_amdgcn_mfma_f32_16x16x32_f16(afr, Bf[cur][0], acc[mf][0], 0, 0, 0);
            acc[mf][1] = __builtin_amdgcn_mfma_f32_16x16x32_f16(afr, Bf[cur][1], acc[mf][1], 0, 0, 0);
        }
        __syncthreads();   // drains vmcnt; also separates staging from epilogue
    }

    // ---- transform + stage to LDS (f16, 144 rows x 128 px, pad to 132) ----
    const bool is_off = (blockIdx.y < 2);     // block-uniform channel class
    float flY[2], flX[2];
#pragma unroll
    for (int nf = 0; nf < 2; ++nf) {
        const int px = px0 + nf * 16 + l15;
        if (is_off) {
            flY[nf] = flow[(size_t)(b * 2 + 1) * HW_ + y * W_ + px]; // slot 0 (y)
            flX[nf] = flow[(size_t)(b * 2 + 0) * HW_ + y * W_ + px]; // slot 1 (x)
        }
    }
#pragma unroll
    for (int mf = 0; mf < 9; ++mf) {
        const float4 b4 = *(const float4*)&bias[m0 + mf * 16 + quad * 4];
#pragma unroll
        for (int nf = 0; nf < 2; ++nf) {
            const int px = px0 + nf * 16 + l15;
#pragma unroll
            for (int reg = 0; reg < 4; ++reg) {
                const int ocl = mf * 16 + quad * 4 + reg;   // 0..143
                float val = acc[mf][nf][reg] + ((const float*)&b4)[reg];
                if (is_off) {                       // offset channels
                    const int slot = reg & 1;       // 0 = y, 1 = x
                    const float fl = slot ? flX[nf] : flY[nf];
                    const float e = __expf(2.f * val);      // tanh via exp
                    val = 10.f * (1.f - __fdividef(2.f, e + 1.f)) + fl;
                } else {                            // mask channels: sigmoid
                    val = __fdividef(1.f, 1.f + __expf(-val));
                }
                Lds[ocl * 132 + px] = (_Float16)val;
            }
        }
    }
    __syncthreads();   // LDS read-only hereafter

    // ---- contiguous f16 copy-out: 144 plane-rows x 128 px ----
#pragma unroll
    for (int it = 0; it < 18; ++it) {
        const int j4 = it * 256 + tid;
        const int r  = j4 >> 5;          // 0..143
        const int c4 = j4 & 31;          // half4 col
        const int oc = m0 + r;
        int g, k, slot;
        if (oc < 2 * DG_ * KK_) {
            g = oc / 18;
            const int rem = oc - g * 18;
            k = rem >> 1;
            slot = rem & 1;
        } else {
            const int c = oc - 2 * DG_ * KK_;
            g = c / 9;
            k = c - g * 9;
            slot = 2;
        }
        const half4 hv = *(const half4*)&Lds[r * 132 + c4 * 4];
        *(half4*)&omh[((size_t)((b * DG_ * KK_ + g * KK_ + k) * 3 + slot)) * HW_
                      + y * W_ + c4 * 4] = hv;
    }
}

// ---------------------------------------------------------------------------
// Phase A: bilinear gather, PIXEL-MAJOR lanes. Thread = one pixel for a
// fixed (b,k); loops g=0..15 in registers.
// ---------------------------------------------------------------------------
__global__ __launch_bounds__(256) void gather_k(
    const _Float16* __restrict__ xg, const _Float16* __restrict__ omh,
    _Float16* __restrict__ valh)
{
    const int tid = threadIdx.x;
    const int pix = blockIdx.x * 256 + tid;
    const int zy  = blockIdx.y;               // b*9 + k
    const int b   = zy / KK_;
    const int k   = zy - b * KK_;
    const int yp  = pix >> 7;
    const int xp  = pix & (W_ - 1);
    const float fy = (float)(yp + (k / 3) - 1);
    const float fx = (float)(xp + (k % 3) - 1);

    half4 rec[16];
#pragma unroll
    for (int g = 0; g < DG_; ++g) {
        const size_t obase = ((size_t)((b * DG_ + g) * KK_ + k) * 3) * HW_ + pix;
        const float oy = (float)omh[obase];
        const float ox = (float)omh[obase + HW_];
        const float m  = (float)omh[obase + 2 * HW_];

        const float py = fy + oy;
        const float px = fx + ox;
        const float y0f = floorf(py);
        const float x0f = floorf(px);
        const float wy = py - y0f;
        const float wx = px - x0f;
        const int y0 = (int)y0f, x0 = (int)x0f;
        const int y1 = y0 + 1,  x1 = x0 + 1;
        const bool vy0 = ((unsigned)y0 < (unsigned)H_);
        const bool vy1 = ((unsigned)y1 < (unsigned)H_);
        const bool vx0 = ((unsigned)x0 < (unsigned)W_);
        const bool vx1 = ((unsigned)x1 < (unsigned)W_);
        const float w00 = vy0 && vx0 ? (1.f - wy) * (1.f - wx) : 0.f;
        const float w01 = vy0 && vx1 ? (1.f - wy) * wx         : 0.f;
        const float w10 = vy1 && vx0 ? wy * (1.f - wx)         : 0.f;
        const float w11 = vy1 && vx1 ? wy * wx                 : 0.f;
        const int i00 = (vy0 && vx0) ? y0 * W_ + x0 : 0;
        const int i01 = (vy0 && vx1) ? y0 * W_ + x1 : 0;
        const int i10 = (vy1 && vx0) ? y1 * W_ + x0 : 0;
        const int i11 = (vy1 && vx1) ? y1 * W_ + x1 : 0;

        const _Float16* xb = xg + (size_t)(b * DG_ + g) * HW_ * 4;
        const half4 p00 = *(const half4*)&xb[(size_t)i00 * 4];
        const half4 p01 = *(const half4*)&xb[(size_t)i01 * 4];
        const half4 p10 = *(const half4*)&xb[(size_t)i10 * 4];
        const half4 p11 = *(const half4*)&xb[(size_t)i11 * 4];

        half4 v4;
#pragma unroll
        for (int c = 0; c < CG_; ++c) {
            float v = w00 * (float)p00[c] + w01 * (float)p01[c]
                    + w10 * (float)p10[c] + w11 * (float)p11[c];
            v4[c] = (_Float16)(v * m);
        }
        rec[g] = v4;
    }

    // write slabs s = 2k (g 0..7) and 2k+1 (g 8..15): 64 B each, contiguous
    _Float16* r0 = &valh[((size_t)((2 * k) * B_ + b) * HW_ + pix) * 32];
    _Float16* r1 = &valh[((size_t)((2 * k + 1) * B_ + b) * HW_ + pix) * 32];
#pragma unroll
    for (int j = 0; j < 4; ++j) {
        half8 w0, w1;
#pragma unroll
        for (int c = 0; c < 4; ++c) {
            w0[c]     = rec[2 * j][c];
            w0[c + 4] = rec[2 * j + 1][c];
            w1[c]     = rec[8 + 2 * j][c];
            w1[c + 4] = rec[9 + 2 * j][c];
        }
        *(half8*)&r0[j * 8] = w0;
        *(half8*)&r1[j * 8] = w1;
    }
}

// ---------------------------------------------------------------------------
// Phase B: einsum via f16 MFMA. Wave = 16 px x 64 oc (mf=4).
// v4: 2-phase LDS pipeline on A (wkA, shared by all waves); B (streamed valh)
// prefetched to regs one step ahead. Staging aliases the epilogue LDS.
// ---------------------------------------------------------------------------
__global__ __launch_bounds__(256, 2) void einsum_mfma_k(
    const _Float16* __restrict__ valh, const _Float16* __restrict__ wkA,
    float* __restrict__ out)
{
    __shared__ __align__(16) float Smem[64 * 68];  // 17408 B (union)
    _Float16* Asm = (_Float16*)Smem;               // A dbuf: 2 x 2048 f16 (8 KB)
    float*    Lds = Smem;                          // epilogue view

    const int tid  = threadIdx.x;
    const int lane = tid & 63;
    const int wv   = tid >> 6;
    const int l15  = lane & 15;
    const int quad = lane >> 4;

    const int pixg0 = blockIdx.x * 64 + wv * 16;    // global pixel (b*HW+pix)
    const int b     = pixg0 >> 14;
    const int pix0  = pixg0 & (HW_ - 1);

    const int sA = afrag_src(tid);

    floatx4 acc[4];
#pragma unroll
    for (int mf = 0; mf < 4; ++mf)
        acc[mf] = (floatx4){0.f, 0.f, 0.f, 0.f};

    half8 Bf[2];

    // prologue: stage A step 0, load B step 0
    gl_lds16(wkA + sA, Asm + tid * 8);
    Bf[0] = *(const half8*)&valh[((size_t)(0 * B_ + b) * HW_ + pix0 + l15) * 32 + quad * 8];
    __syncthreads();

#pragma unroll
    for (int s = 0; s < 18; ++s) {
        const int cur = s & 1, nxt = cur ^ 1;
        if (s < 17) {
            const int s1 = s + 1;
            gl_lds16(wkA + (size_t)s1 * 2048 + sA, Asm + nxt * 2048 + tid * 8);
            Bf[nxt] = *(const half8*)&valh[
                ((size_t)(s1 * B_ + b) * HW_ + pix0 + l15) * 32 + quad * 8];
        }
        const _Float16* abase = Asm + cur * 2048 + lane * 8;
#pragma unroll
        for (int mf = 0; mf < 4; ++mf) {
            const half8 afr = *(const half8*)&abase[mf * 512];
            acc[mf] = __builtin_amdgcn_mfma_f32_16x16x32_f16(afr, Bf[cur], acc[mf], 0, 0, 0);
        }
        __syncthreads();   // drains vmcnt; final one separates staging/epilogue
    }

    // ---- stage 64 oc x 64 px tile to LDS ----
    const int pxl = wv * 16 + l15;                  // 0..63 block-local pixel
#pragma unroll
    for (int mf = 0; mf < 4; ++mf)
#pragma unroll
        for (int reg = 0; reg < 4; ++reg)
            Lds[(mf * 16 + quad * 4 + reg) * 68 + pxl] = acc[mf][reg];
    __syncthreads();   // LDS read-only hereafter

    // ---- coalesced copy-out: 64 oc-rows x 64 px (16 float4 per row) ----
    const int pixb = blockIdx.x * 64 & (HW_ - 1);   // block-base pixel
#pragma unroll
    for (int it = 0; it < 4; ++it) {
        const int j4 = it * 256 + tid;
        const int r  = j4 >> 4;                     // oc 0..63
        const int c4 = j4 & 15;                     // float4 col
        float4 v;
        v.x = Lds[r * 68 + c4 * 4 + 0];
        v.y = Lds[r * 68 + c4 * 4 + 1];
        v.z = Lds[r * 68 + c4 * 4 + 2];
        v.w = Lds[r * 68 + c4 * 4 + 3];
        *(float4*)&out[((size_t)(b * C_ + r)) * HW_ + pixb + c4 * 4] = v;
    }
}

// ---------------------------------------------------------------------------
extern "C" void kernel_launch(void* const* d_in, const int* in_sizes, int n_in,
                              void* d_out, int out_size, void* d_ws, size_t ws_size,
                              hipStream_t stream)
{
    const float* x    = (const float*)d_in[0];
    const float* ef   = (const float*)d_in[1];
    const float* flow = (const float*)d_in[2];
    const float* w1   = (const float*)d_in[3];
    const float* b1   = (const float*)d_in[4];
    const float* w2   = (const float*)d_in[5];
    const float* b2   = (const float*)d_in[6];
    const float* w3   = (const float*)d_in[7];
    const float* b3   = (const float*)d_in[8];
    const float* wk   = (const float*)d_in[9];
    float* out = (float*)d_out;

    // Workspace (half slots):
    //   omh 14,155,776 | valh 18,874,368 | ef_p 4*B*HWP*32 = 4,326,400
    //   xg 2,097,152 | h1p 2*B*HWP*32 = 2,163,200 | h2p 2,163,200
    //   w1A 73,728 | w2A 36,864 | w3A 248,832 | wkA 36,864
    _Float16* omh  = (_Float16*)d_ws;
    _Float16* valh = omh + (size_t)B_ * OFFC_ * HW_;
    _Float16* ef_p = valh + (size_t)18 * B_ * HW_ * 32;
    _Float16* xg   = ef_p + (size_t)4 * B_ * HWP_ * 32;
    _Float16* h1p  = xg + (size_t)B_ * HW_ * 64;
    _Float16* h2p  = h1p + (size_t)2 * B_ * HWP_ * 32;
    _Float16* w1A  = h2p + (size_t)2 * B_ * HWP_ * 32;
    _Float16* w2A  = w1A + 64 * 128 * 9;
    _Float16* w3A  = w2A + 64 * 64 * 9;
    _Float16* wkA  = w3A + OFFC_ * 64 * 9;

    // Zero the padded buffers (borders must be 0; interiors overwritten).
    hipMemsetAsync(ef_p, 0, (size_t)4 * B_ * HWP_ * 32 * 2, stream);
    hipMemsetAsync(h1p, 0, (size_t)2 * B_ * HWP_ * 32 * 2, stream);
    hipMemsetAsync(h2p, 0, (size_t)2 * B_ * HWP_ * 32 * 2, stream);

    prep_wA_k<64, 128><<<dim3((64 * 128 * 9 + 255) / 256), 256, 0, stream>>>(w1, w1A);
    prep_wA_k<64, 64><<<dim3((64 * 64 * 9 + 255) / 256), 256, 0, stream>>>(w2, w2A);
    prep_wA_k<OFFC_, 64><<<dim3((OFFC_ * 64 * 9 + 255) / 256), 256, 0, stream>>>(w3, w3A);
    prep_wkA_k<<<dim3((18 * 64 * 32 + 255) / 256), 256, 0, stream>>>(wk, wkA);
    nchw2slabpad_f16_k<128><<<dim3(HW_ / 256, B_), 256, 0, stream>>>(ef, ef_p);
    nchw2gx_f16_k<<<dim3(HW_ / 256, B_), 256, 0, stream>>>(x, xg);

    conv12_mfma_k<128><<<dim3(B_ * H_ * 2), 256, 0, stream>>>(ef_p, w1A, b1, h1p);
    conv12_mfma_k<64><<<dim3(B_ * H_ * 2), 256, 0, stream>>>(h1p, w2A, b2, h2p);
    conv3_mfma_k<<<dim3(B_ * H_, 3), 256, 0, stream>>>(h2p, w3A, b3, flow, omh);

    gather_k<<<dim3(HW_ / 256, B_ * KK_), 256, 0, stream>>>(xg, omh, valh);
    einsum_mfma_k<<<dim3(B_ * HW_ / 64), 256, 0, stream>>>(valh, wkA, out);
}